// Round 7
// baseline (1153.150 us; speedup 1.0000x reference)
//
#include <hip/hip_runtime.h>
#include <hip/hip_bf16.h>
#include <math.h>

#define NN 3000
#define NP 3072          // padded node dim
#define KA 3008          // A-operand row stride (bf16 elems), k=node padded
#define KB 9024          // adj bf16 row stride
#define MY 3072          // Y fp32 row stride (padded node dim)
#define BD 8
#define TD 10
#define T0D 12
#define WD 8
#define TSLAB (512L*KA)  // bf16 elems per t-slab / d' slab
#define YSLAB (512L*MY)  // fp32 elems per Y slab
#define MSLAB (512L*KA)  // fp32 elems per maxd slab

typedef __attribute__((ext_vector_type(8))) short short8;
typedef __attribute__((ext_vector_type(4))) float floatx4;

__device__ __forceinline__ float sigm(float x) { return 1.0f / (1.0f + __expf(-x)); }
__device__ __forceinline__ ushort f2b(float f) {
    __hip_bfloat16 h = __float2bfloat16(f);
    return *reinterpret_cast<ushort*>(&h);
}
__device__ __forceinline__ void ld_lds16(const void* g, void* l) {
    __builtin_amdgcn_global_load_lds((const __attribute__((address_space(1))) unsigned int*)g,
                                     (__attribute__((address_space(3))) unsigned int*)l, 16, 0, 0);
}

// Fused prep: one launch replaces prep_adj/prep_xt/prep_db(data)/prep_db(orig)/prep_wb.
// Block ranges:
//   [0, 27072)          adj  (3000x9000 f32 -> 3072x9024 bf16, pads zero)
//   [27072, 30832)      xt   (xT2[t][b*64+c][m] = data+temb+semb, transposed)
//   [30832, 46192)      db(data, TD)
//   [46192, 64624)      db(orig, T0D)
//   [64624, 64880)      wb   (conv weight permute+pack)
__global__ __launch_bounds__(256) void prep_all(
    const float* __restrict__ adj, const float* __restrict__ data,
    const float* __restrict__ orig, const float* __restrict__ temb,
    const float* __restrict__ semb, const float* __restrict__ c1w,
    const float* __restrict__ c2w,
    ushort* __restrict__ adjb, ushort* __restrict__ xT2,
    ushort* __restrict__ datab, ushort* __restrict__ origb,
    ushort* __restrict__ wb)
{
    const int blk = blockIdx.x;
    const int tid = threadIdx.x;
    __shared__ float T[64][68];

    if (blk < 27072) {
        long i = (long)blk * 256 + tid;          // 3072*2256 quads
        if (i >= 3072L * 2256) return;
        int r  = (int)(i / 2256);
        int c4 = (int)(i % 2256) * 4;
        ushort4 u = {0, 0, 0, 0};
        if (r < NN && c4 < 9000) {
            float4 v = *(const float4*)(adj + (long)r * 9000 + c4);
            u.x = f2b(v.x); u.y = f2b(v.y); u.z = f2b(v.z); u.w = f2b(v.w);
        }
        *(ushort4*)(adjb + (long)r * KB + c4) = u;
    } else if (blk < 30832) {
        int id = blk - 27072;                    // x + 47*(b + 8*t)
        const int x = id % 47;  id /= 47;
        const int b = id & 7;
        const int t = id >> 3;
        const int m0 = x * 64;
        const int tx = tid & 15, ty = tid >> 4;
        #pragma unroll
        for (int p = 0; p < 4; ++p) {
            int nl = p * 16 + ty;
            int n = m0 + nl;
            int c4 = tx * 4;
            float4 v = {0.f, 0.f, 0.f, 0.f};
            if (n < NN) {
                float4 dv = *(const float4*)(data + ((long)(b * TD + t) * NN + n) * 64 + c4);
                float4 tv = *(const float4*)(temb + t * 64 + c4);
                float4 sv = *(const float4*)(semb + n * 64 + c4);
                v.x = dv.x + tv.x + sv.x; v.y = dv.y + tv.y + sv.y;
                v.z = dv.z + tv.z + sv.z; v.w = dv.w + tv.w + sv.w;
            }
            T[c4 + 0][nl] = v.x; T[c4 + 1][nl] = v.y;
            T[c4 + 2][nl] = v.z; T[c4 + 3][nl] = v.w;
        }
        __syncthreads();
        #pragma unroll
        for (int p = 0; p < 4; ++p) {
            int c = p * 16 + ty;
            int m4 = tx * 4;
            ushort4 u;
            u.x = f2b(T[c][m4 + 0]); u.y = f2b(T[c][m4 + 1]);
            u.z = f2b(T[c][m4 + 2]); u.w = f2b(T[c][m4 + 3]);
            *(ushort4*)(xT2 + ((long)t * 512 + b * 64 + c) * KA + m0 + m4) = u;
        }
    } else if (blk < 64624) {
        const int isData = (blk < 46192);
        const int base = isData ? 30832 : 46192;
        const int Tt = isData ? TD : T0D;
        const float* src = isData ? data : orig;
        ushort* dst = isData ? datab : origb;
        long i = (long)(blk - base) * 256 + tid; // quads: 8*Tt*3072*16
        long tot = 8L * Tt * NP * 16;
        if (i >= tot) return;
        int c4 = (int)(i & 15) * 4;
        long r = i >> 4;                 // (b*Tt+t)*3072 + n
        int n = (int)(r % NP);
        long bt = r / NP;
        ushort4 u = {0, 0, 0, 0};
        if (n < NN) {
            float4 v = *(const float4*)(src + (bt * NN + n) * 64 + c4);
            u.x = f2b(v.x); u.y = f2b(v.y); u.z = f2b(v.z); u.w = f2b(v.w);
        }
        *(ushort4*)(dst + r * 64 + c4) = u;
    } else {
        int i = (blk - 64624) * 256 + tid;
        if (i >= 128 * 512) return;
        int r = i >> 9, k = i & 511;
        int q = r >> 6, jp = r & 63;
        int o = (jp < 32) ? (q * 32 + jp) : (64 + q * 32 + (jp - 32));
        int s = k >> 6, c = k & 63;
        float v = (s < 3) ? c1w[(o * 64 + c) * 3 + s] : c2w[(o * 64 + c) * 5 + (s - 3)];
        wb[i] = f2b(v);
    }
}

// Issue one 128x32 A-tile + 128x32 B-tile stage (4 global_load_lds per wave).
// Rolling global pointers; seg switch after stage 93. Sources are pre-swizzled
// per-lane (kswz folded into gA/gB) so the LINEAR LDS writes store the
// bank-swizzled layout (rule: linear dest + inv-swizzled source + swizzled read).
__device__ __forceinline__ void issue_stage(
    const ushort*& gA, const ushort*& gB, int& stg,
    const ushort* aA1, const ushort* aB1,
    ushort* dA, ushort* dB, int wOff)
{
    ld_lds16(gA,           dA + wOff);
    ld_lds16(gA + 64 * KA, dA + 2048 + wOff);
    ld_lds16(gB,           dB + wOff);
    ld_lds16(gB + 64 * KB, dB + 2048 + wOff);
    ++stg;
    if (stg == 94) { gA = aA1; gB = aB1; }
    else           { gA += 32; gB += 32; }
}

// MFMA GEMM body: Y[j][m] = sum_seg sum_k A_seg[j][k] * B[m][colOff_seg + k]
// 3-buffer pipeline with COUNTED vmcnt (T4): stage s+2 issues before compute
// of step s; after MFMA, s_waitcnt vmcnt(4) retires only stage s+1 (stage s+2
// stays in flight ACROSS the raw s_barrier). Never vmcnt(0) in steady state.
// LDS bank swizzle: slot ^= (row>>1)&3 -> conflicts measured 2.77e7 -> 0 (R6).
__device__ __forceinline__ void gemm_body(
    const ushort* __restrict__ A0, const ushort* __restrict__ A1, int nseg,
    const ushort* __restrict__ Badj, int colOff0, int colOff1,
    float* __restrict__ Yp)
{
    const int m0 = blockIdx.x * 128;
    const int j0 = blockIdx.y * 128;
    const int tid = threadIdx.x;
    const int lane = tid & 63;
    const int wv = tid >> 6;
    __shared__ ushort shA[3][4096];
    __shared__ ushort shB[3][4096];
    floatx4 acc[4][4] = {};
    const int srow = wv * 16 + (lane >> 2);
    const int kswz = ((lane & 3) ^ ((lane >> 3) & 3)) * 8;   // pre-swizzled source slot
    const int wj = (wv >> 1) * 64, wm = (wv & 1) * 64;
    const int half = lane >> 4;
    const int rsub = lane & 15;
    const int hsw  = (half ^ ((rsub >> 1) & 3)) * 8;         // swizzled read slot
    const int wOff = wv * 512;
    const int nkt = 94 * nseg;

    // loop-invariant LDS read offsets (elems)
    int offA[4], offB[4];
    #pragma unroll
    for (int i = 0; i < 4; ++i) {
        offA[i] = (wj + i * 16 + rsub) * 32 + hsw;
        offB[i] = (wm + i * 16 + rsub) * 32 + hsw;
    }

    const ushort* aA1 = A1 + (long)(j0 + srow) * KA + kswz;
    const ushort* aB1 = Badj + colOff1 + (long)(m0 + srow) * KB + kswz;
    const ushort* gA  = A0 + (long)(j0 + srow) * KA + kswz;
    const ushort* gB  = Badj + colOff0 + (long)(m0 + srow) * KB + kswz;
    int stg = 0;

    ushort *pA0 = shA[0], *pA1 = shA[1], *pA2 = shA[2];
    ushort *pB0 = shB[0], *pB1 = shB[1], *pB2 = shB[2];

    // prologue: stages 0,1 in flight; retire stage 0 only
    issue_stage(gA, gB, stg, aA1, aB1, pA0, pB0, wOff);
    issue_stage(gA, gB, stg, aA1, aB1, pA1, pB1, wOff);
    asm volatile("s_waitcnt vmcnt(4)" ::: "memory");
    __builtin_amdgcn_s_barrier();
    __builtin_amdgcn_sched_barrier(0);

    for (int s = 0; s < nkt; ++s) {
        if (s + 2 < nkt)
            issue_stage(gA, gB, stg, aA1, aB1, pA2, pB2, wOff);
        short8 af[4], bf[4];
        #pragma unroll
        for (int i = 0; i < 4; ++i)
            af[i] = *(const short8*)(pA0 + offA[i]);
        #pragma unroll
        for (int i = 0; i < 4; ++i)
            bf[i] = *(const short8*)(pB0 + offB[i]);
        #pragma unroll
        for (int i = 0; i < 4; ++i)
            #pragma unroll
            for (int jj = 0; jj < 4; ++jj)
                acc[i][jj] = __builtin_amdgcn_mfma_f32_16x16x32_bf16(af[i], bf[jj], acc[i][jj], 0, 0, 0);
        // retire stage s+1 (to be read next step); keep stage s+2 in flight
        if (s + 2 < nkt) {
            asm volatile("s_waitcnt vmcnt(4)" ::: "memory");
        } else if (s + 1 < nkt) {
            asm volatile("s_waitcnt vmcnt(0)" ::: "memory");
        }
        __builtin_amdgcn_s_barrier();
        __builtin_amdgcn_sched_barrier(0);
        ushort* t;
        t = pA0; pA0 = pA1; pA1 = pA2; pA2 = t;
        t = pB0; pB0 = pB1; pB1 = pB2; pB2 = t;
    }

    #pragma unroll
    for (int i = 0; i < 4; ++i) {
        int jrow = j0 + wj + i * 16 + half * 4;
        #pragma unroll
        for (int jj = 0; jj < 4; ++jj) {
            int mcol = m0 + wm + jj * 16 + rsub;
            float* o = Yp + (long)jrow * MY + mcol;
            o[0L * MY] = acc[i][jj].x;
            o[1L * MY] = acc[i][jj].y;
            o[2L * MY] = acc[i][jj].z;
            o[3L * MY] = acc[i][jj].w;
        }
    }
}

// Generic per-w wrapper (used for d1/d2 rounds)
__global__ __launch_bounds__(256) void gemm_mfma(
    const ushort* __restrict__ A0, const ushort* __restrict__ A1, int nseg, long aW,
    const ushort* __restrict__ Badj, int colOff0, int colOff1,
    float* __restrict__ Y)
{
    const int w = blockIdx.z;
    gemm_body(A0 + (long)w * aW, A1 + (long)w * aW, nseg,
              Badj, colOff0, colOff1, Y + (long)w * YSLAB);
}

// Combined wing + d0 launch: z<8 -> wing (nseg=2), z>=8 -> d0 (nseg=1).
__global__ __launch_bounds__(256) void gemm_wing_d0(
    const ushort* __restrict__ xT2, const ushort* __restrict__ Badj,
    float* __restrict__ ywing, float* __restrict__ yd)
{
    const int zz = blockIdx.z;
    if (zz < 8) {
        gemm_body(xT2 + (long)zz * TSLAB, xT2 + (long)(zz + 1) * TSLAB, 2,
                  Badj, 0, 3000, ywing + (long)zz * YSLAB);
    } else {
        const int w = zz - 8;
        const ushort* a = xT2 + (long)(w + 2) * TSLAB;
        gemm_body(a, a, 1, Badj, 6000, 0, yd + (long)w * YSLAB);
    }
}

// Gated convs via MFMA, now with the verified 3-stage counted-vmcnt pipeline
// + bank swizzle. Per (b,wt): Z[n][o'] = sum_k A[n][k] * wb[o'][k], K=512.
// Stage kt: s=kt>>1 selects source slab, koff=(kt&1)*32.
// Compute step s<6 -> acc1 (conv1/data), else acc2 (conv2/orig).
__global__ __launch_bounds__(256) void conv_mfma(
    const ushort* __restrict__ datab, const ushort* __restrict__ origb,
    const ushort* __restrict__ wb,
    const float* __restrict__ b1, const float* __restrict__ b2,
    float* __restrict__ out)
{
    const int b = blockIdx.y >> 3, wt = blockIdx.y & 7;
    const int n0 = blockIdx.x * 128;
    const int tid = threadIdx.x;
    const int lane = tid & 63;
    const int wv = tid >> 6;
    __shared__ ushort shA[3][4096];
    __shared__ ushort shB[3][4096];
    floatx4 acc1[4][4] = {};
    floatx4 acc2[4][4] = {};
    const int srow = wv * 16 + (lane >> 2);
    const int kswz = ((lane & 3) ^ ((lane >> 3) & 3)) * 8;
    const int wj = (wv >> 1) * 64, wm = (wv & 1) * 64;
    const int half = lane >> 4;
    const int rsub = lane & 15;
    const int hsw  = (half ^ ((rsub >> 1) & 3)) * 8;
    const int wOff = wv * 512;

    int offA[4], offB[4];
    #pragma unroll
    for (int i = 0; i < 4; ++i) {
        offA[i] = (wj + i * 16 + rsub) * 32 + hsw;
        offB[i] = (wm + i * 16 + rsub) * 32 + hsw;
    }

    auto stage = [&](int kt, ushort* dA, ushort* dB) {
        const int sl = kt >> 1, koff = (kt & 1) * 32;
        const ushort* Ab = (sl < 3) ? datab + (long)(b * TD + wt + sl) * NP * 64
                                    : origb + (long)(b * T0D + wt + (sl - 3)) * NP * 64;
        const ushort* gA = Ab + (long)(n0 + srow) * 64 + koff + kswz;
        ld_lds16(gA,           dA + wOff);
        ld_lds16(gA + 64 * 64, dA + 2048 + wOff);
        const ushort* gB = wb + (long)srow * 512 + kt * 32 + kswz;
        ld_lds16(gB,            dB + wOff);
        ld_lds16(gB + 64 * 512, dB + 2048 + wOff);
    };

    ushort *pA0 = shA[0], *pA1 = shA[1], *pA2 = shA[2];
    ushort *pB0 = shB[0], *pB1 = shB[1], *pB2 = shB[2];

    stage(0, pA0, pB0);
    stage(1, pA1, pB1);
    asm volatile("s_waitcnt vmcnt(4)" ::: "memory");
    __builtin_amdgcn_s_barrier();
    __builtin_amdgcn_sched_barrier(0);

    for (int s = 0; s < 16; ++s) {
        if (s + 2 < 16)
            stage(s + 2, pA2, pB2);
        short8 af[4], bf[4];
        #pragma unroll
        for (int i = 0; i < 4; ++i)
            af[i] = *(const short8*)(pA0 + offA[i]);
        #pragma unroll
        for (int i = 0; i < 4; ++i)
            bf[i] = *(const short8*)(pB0 + offB[i]);
        if (s < 6) {
            #pragma unroll
            for (int i = 0; i < 4; ++i)
                #pragma unroll
                for (int jj = 0; jj < 4; ++jj)
                    acc1[i][jj] = __builtin_amdgcn_mfma_f32_16x16x32_bf16(af[i], bf[jj], acc1[i][jj], 0, 0, 0);
        } else {
            #pragma unroll
            for (int i = 0; i < 4; ++i)
                #pragma unroll
                for (int jj = 0; jj < 4; ++jj)
                    acc2[i][jj] = __builtin_amdgcn_mfma_f32_16x16x32_bf16(af[i], bf[jj], acc2[i][jj], 0, 0, 0);
        }
        if (s + 2 < 16) {
            asm volatile("s_waitcnt vmcnt(4)" ::: "memory");
        } else if (s + 1 < 16) {
            asm volatile("s_waitcnt vmcnt(0)" ::: "memory");
        }
        __builtin_amdgcn_s_barrier();
        __builtin_amdgcn_sched_barrier(0);
        ushort* t;
        t = pA0; pA0 = pA1; pA1 = pA2; pA2 = t;
        t = pB0; pB0 = pB1; pB1 = pB2; pB2 = t;
    }

    const int q = wv & 1;
    float* outp = out + (long)(b * WD + wt) * NN * 64;
    #pragma unroll
    for (int i = 0; i < 4; ++i) {
        const int nbase = n0 + wj + i * 16 + half * 4;
        #pragma unroll
        for (int jj = 0; jj < 2; ++jj) {
            const int ol = q * 32 + jj * 16 + rsub;           // output col c (0..63)
            const float bl1 = b1[ol], br1 = b1[64 + ol];
            const float bl2 = b2[ol], br2 = b2[64 + ol];
            float zl1[4] = {acc1[i][jj].x, acc1[i][jj].y, acc1[i][jj].z, acc1[i][jj].w};
            float zr1[4] = {acc1[i][jj+2].x, acc1[i][jj+2].y, acc1[i][jj+2].z, acc1[i][jj+2].w};
            float zl2[4] = {acc2[i][jj].x, acc2[i][jj].y, acc2[i][jj].z, acc2[i][jj].w};
            float zr2[4] = {acc2[i][jj+2].x, acc2[i][jj+2].y, acc2[i][jj+2].z, acc2[i][jj+2].w};
            #pragma unroll
            for (int r = 0; r < 4; ++r) {
                int n = nbase + r;
                if (n < NN) {
                    float ov = sigm(zl1[r] + bl1) * (zr1[r] + br1)
                             + sigm(zl2[r] + bl2) * (zr2[r] + br2);
                    outp[(long)n * 64 + ol] = ov;
                }
            }
        }
    }
}

// GLU in transposed space, b split across blockIdx.z for occupancy (376->3008
// blocks): per (w,b): Z[o][m] = sum_c gw[c][o] * (Yd+Ywing)[b*64+c][m]
__global__ __launch_bounds__(256) void glu_t(
    const float* __restrict__ Yd, const float* __restrict__ Ywing,
    const float* __restrict__ gw_all, const float* __restrict__ gb_all,
    int kIdx, ushort* __restrict__ dp, float* __restrict__ maxd)
{
    const int w = blockIdx.y;
    const int b = blockIdx.z;
    const int m0 = blockIdx.x * 64;
    const int tid = threadIdx.x;
    const int tx = tid & 15, ty = tid >> 4;
    const float* Ydp = Yd + (long)w * YSLAB;
    const float* Ywp = Ywing + (long)w * YSLAB;
    ushort* dpp = dp + (long)w * TSLAB;
    float* mdp = maxd + (long)w * MSLAB;
    const float* gw = gw_all + (long)(w * 3 + kIdx) * 8192;
    const float* gb = gb_all + (w * 3 + kIdx) * 128;
    __shared__ float gws[64][132];
    __shared__ float Ys[64][68];
    #pragma unroll
    for (int p = 0; p < 8; ++p) {
        int r = p * 8 + (tid >> 5);
        int c0 = (tid & 31) * 4;
        *(float4*)&gws[r][c0] = *(const float4*)(gw + r * 128 + c0);
    }
    #pragma unroll
    for (int p = 0; p < 4; ++p) {
        int c = p * 16 + ty;
        long off = (long)(b * 64 + c) * MY + m0 + tx * 4;
        float4 v1 = *(const float4*)(Ydp + off);
        float4 v2 = *(const float4*)(Ywp + off);
        Ys[c][tx * 4 + 0] = v1.x + v2.x;
        Ys[c][tx * 4 + 1] = v1.y + v2.y;
        Ys[c][tx * 4 + 2] = v1.z + v2.z;
        Ys[c][tx * 4 + 3] = v1.w + v2.w;
    }
    __syncthreads();
    float acc[8][4] = {{0.f}};
    for (int c = 0; c < 64; ++c) {
        float4 ym = *(const float4*)&Ys[c][tx * 4];
        #pragma unroll
        for (int p = 0; p < 8; ++p) {
            float a = gws[c][ty + p * 16];
            acc[p][0] = fmaf(a, ym.x, acc[p][0]);
            acc[p][1] = fmaf(a, ym.y, acc[p][1]);
            acc[p][2] = fmaf(a, ym.z, acc[p][2]);
            acc[p][3] = fmaf(a, ym.w, acc[p][3]);
        }
    }
    #pragma unroll
    for (int p = 0; p < 4; ++p) {
        int c = ty + p * 16;
        float bl = gb[c], br = gb[64 + c];
        long row = (long)(b * 64 + c) * KA + m0 + tx * 4;
        float d[4];
        #pragma unroll
        for (int q = 0; q < 4; ++q) {
            float zl = acc[p][q] + bl;
            float zr = acc[p + 4][q] + br;
            d[q] = zl * sigm(zr);
        }
        int mb = m0 + tx * 4;
        if (kIdx < 2) {
            ushort4 u;
            u.x = (mb + 0 < NN) ? f2b(d[0]) : (ushort)0;
            u.y = (mb + 1 < NN) ? f2b(d[1]) : (ushort)0;
            u.z = (mb + 2 < NN) ? f2b(d[2]) : (ushort)0;
            u.w = (mb + 3 < NN) ? f2b(d[3]) : (ushort)0;
            *(ushort4*)(dpp + row) = u;
        }
        if (kIdx == 0) {
            float4 m4 = {d[0], d[1], d[2], d[3]};
            *(float4*)(mdp + row) = m4;
        } else {
            float4 old = *(const float4*)(mdp + row);
            float4 m4;
            m4.x = fmaxf(old.x, d[0]); m4.y = fmaxf(old.y, d[1]);
            m4.z = fmaxf(old.z, d[2]); m4.w = fmaxf(old.w, d[3]);
            *(float4*)(mdp + row) = m4;
        }
    }
}

// out[b][w][n][c] += maxd[w][b*64+c][n] (LDS transpose) + (data+temb+semb)[b][w+2][n][c]
__global__ __launch_bounds__(256) void final_t(
    const float* __restrict__ maxd, const float* __restrict__ data,
    const float* __restrict__ temb, const float* __restrict__ semb,
    float* __restrict__ out)
{
    const int w = blockIdx.z, b = blockIdx.y;
    const int m0 = blockIdx.x * 64;
    const int tid = threadIdx.x;
    const int tx = tid & 15, ty = tid >> 4;
    const float* mdp = maxd + (long)w * MSLAB;
    __shared__ float T[64][68];
    #pragma unroll
    for (int p = 0; p < 4; ++p) {
        int c = p * 16 + ty;
        float4 v = *(const float4*)(mdp + (long)(b * 64 + c) * KA + m0 + tx * 4);
        T[c][tx * 4 + 0] = v.x; T[c][tx * 4 + 1] = v.y;
        T[c][tx * 4 + 2] = v.z; T[c][tx * 4 + 3] = v.w;
    }
    __syncthreads();
    #pragma unroll
    for (int p = 0; p < 4; ++p) {
        int nl = p * 16 + ty;
        int n = m0 + nl;
        if (n < NN) {
            int c4 = tx * 4;
            long oidx = ((long)(b * WD + w) * NN + n) * 64 + c4;
            float4 o  = *(const float4*)(out + oidx);
            float4 dd = *(const float4*)(data + ((long)(b * TD + w + 2) * NN + n) * 64 + c4);
            float4 tv = *(const float4*)(temb + (w + 2) * 64 + c4);
            float4 sv = *(const float4*)(semb + n * 64 + c4);
            o.x += T[c4 + 0][nl] + dd.x + tv.x + sv.x;
            o.y += T[c4 + 1][nl] + dd.y + tv.y + sv.y;
            o.z += T[c4 + 2][nl] + dd.z + tv.z + sv.z;
            o.w += T[c4 + 3][nl] + dd.w + tv.w + sv.w;
            *(float4*)(out + oidx) = o;
        }
    }
}

extern "C" void kernel_launch(void* const* d_in, const int* in_sizes, int n_in,
                              void* d_out, int out_size, void* d_ws, size_t ws_size,
                              hipStream_t stream) {
    const float* orig = (const float*)d_in[0];
    const float* data = (const float*)d_in[1];
    const float* adj  = (const float*)d_in[2];
    const float* c1w  = (const float*)d_in[3];
    const float* c1b  = (const float*)d_in[4];
    const float* c2w  = (const float*)d_in[5];
    const float* c2b  = (const float*)d_in[6];
    const float* temb = (const float*)d_in[7];
    const float* semb = (const float*)d_in[8];
    const float* gw   = (const float*)d_in[9];
    const float* gb   = (const float*)d_in[10];
    float* out = (float*)d_out;

    char* ws = (char*)d_ws;
    ushort* adjb = (ushort*)ws;                          ws += 3072L * 9024 * 2;   // 55.44 MB
    ushort* xT2  = (ushort*)ws;                          ws += 10L * TSLAB * 2;    // 30.80 MB
    ushort* dpb  = (ushort*)ws;                          ws += 8L * TSLAB * 2;     // 24.64 MB
    float*  ywing = (float*)ws;                          ws += 8L * YSLAB * 4;     // 50.33 MB
    float*  yd    = (float*)ws;                          ws += 8L * YSLAB * 4;     // 50.33 MB
    float*  maxd  = (float*)ws;                          // 49.28 MB  (total ~260.8 MB)

    // Aliases (dead until overwritten by later kernels, in-stream order):
    ushort* wb    = (ushort*)ywing;   // 128 KB, consumed by conv_mfma before wing gemm
    ushort* datab = (ushort*)yd;      // 31.5 MB, consumed before d0 gemm writes yd
    ushort* origb = (ushort*)maxd;    // 37.7 MB, consumed before glu_t writes maxd

    prep_all<<<dim3(64880), 256, 0, stream>>>(adj, data, orig, temb, semb, c1w, c2w,
                                              adjb, xT2, datab, origb, wb);

    conv_mfma<<<dim3(24, 64), 256, 0, stream>>>(datab, origb, wb, c1b, c2b, out);

    // wing + d0 combined (independent outputs; packs tails, saves a launch)
    gemm_wing_d0<<<dim3(24, 4, 16), 256, 0, stream>>>(xT2, adjb, ywing, yd);
    glu_t<<<dim3(47, 8, 8), 256, 0, stream>>>(yd, ywing, gw, gb, 0, dpb, maxd);
    gemm_mfma<<<dim3(24, 4, 8), 256, 0, stream>>>(dpb, dpb, 1, TSLAB, adjb, 6000, 0, yd);
    glu_t<<<dim3(47, 8, 8), 256, 0, stream>>>(yd, ywing, gw, gb, 1, dpb, maxd);
    gemm_mfma<<<dim3(24, 4, 8), 256, 0, stream>>>(dpb, dpb, 1, TSLAB, adjb, 6000, 0, yd);
    glu_t<<<dim3(47, 8, 8), 256, 0, stream>>>(yd, ywing, gw, gb, 2, dpb, maxd);

    final_t<<<dim3(47, 8, 8), 256, 0, stream>>>(maxd, data, temb, semb, out);
}

// Round 11
// 961.761 us; speedup vs baseline: 1.1990x; 1.1990x over previous
//
#include <hip/hip_runtime.h>
#include <hip/hip_bf16.h>
#include <math.h>

#define NN 3000
#define NP 3072          // padded node dim
#define KA 3008          // A-operand row stride (bf16 elems), k=node padded
#define KB 9024          // adj bf16 row stride
#define MY 3072          // Y fp32 row stride (padded node dim)
#define BD 8
#define TD 10
#define T0D 12
#define WD 8
#define TSLAB (512L*KA)  // bf16 elems per t-slab / d' slab
#define YSLAB (512L*MY)  // fp32 elems per Y slab
#define MSLAB (512L*KA)  // fp32 elems per maxd slab

typedef __attribute__((ext_vector_type(8))) short short8;
typedef __attribute__((ext_vector_type(4))) float floatx4;

__device__ __forceinline__ float sigm(float x) { return 1.0f / (1.0f + __expf(-x)); }
__device__ __forceinline__ ushort f2b(float f) {
    __hip_bfloat16 h = __float2bfloat16(f);
    return *reinterpret_cast<ushort*>(&h);
}
__device__ __forceinline__ void ld_lds16(const void* g, void* l) {
    __builtin_amdgcn_global_load_lds((const __attribute__((address_space(1))) unsigned int*)g,
                                     (__attribute__((address_space(3))) unsigned int*)l, 16, 0, 0);
}

// Fused prep: one launch replaces prep_adj/prep_xt/prep_db(data)/prep_db(orig)/prep_wb.
__global__ __launch_bounds__(256) void prep_all(
    const float* __restrict__ adj, const float* __restrict__ data,
    const float* __restrict__ orig, const float* __restrict__ temb,
    const float* __restrict__ semb, const float* __restrict__ c1w,
    const float* __restrict__ c2w,
    ushort* __restrict__ adjb, ushort* __restrict__ xT2,
    ushort* __restrict__ datab, ushort* __restrict__ origb,
    ushort* __restrict__ wb)
{
    const int blk = blockIdx.x;
    const int tid = threadIdx.x;
    __shared__ float T[64][68];

    if (blk < 27072) {
        long i = (long)blk * 256 + tid;          // 3072*2256 quads
        if (i >= 3072L * 2256) return;
        int r  = (int)(i / 2256);
        int c4 = (int)(i % 2256) * 4;
        ushort4 u = {0, 0, 0, 0};
        if (r < NN && c4 < 9000) {
            float4 v = *(const float4*)(adj + (long)r * 9000 + c4);
            u.x = f2b(v.x); u.y = f2b(v.y); u.z = f2b(v.z); u.w = f2b(v.w);
        }
        *(ushort4*)(adjb + (long)r * KB + c4) = u;
    } else if (blk < 30832) {
        int id = blk - 27072;                    // x + 47*(b + 8*t)
        const int x = id % 47;  id /= 47;
        const int b = id & 7;
        const int t = id >> 3;
        const int m0 = x * 64;
        const int tx = tid & 15, ty = tid >> 4;
        #pragma unroll
        for (int p = 0; p < 4; ++p) {
            int nl = p * 16 + ty;
            int n = m0 + nl;
            int c4 = tx * 4;
            float4 v = {0.f, 0.f, 0.f, 0.f};
            if (n < NN) {
                float4 dv = *(const float4*)(data + ((long)(b * TD + t) * NN + n) * 64 + c4);
                float4 tv = *(const float4*)(temb + t * 64 + c4);
                float4 sv = *(const float4*)(semb + n * 64 + c4);
                v.x = dv.x + tv.x + sv.x; v.y = dv.y + tv.y + sv.y;
                v.z = dv.z + tv.z + sv.z; v.w = dv.w + tv.w + sv.w;
            }
            T[c4 + 0][nl] = v.x; T[c4 + 1][nl] = v.y;
            T[c4 + 2][nl] = v.z; T[c4 + 3][nl] = v.w;
        }
        __syncthreads();
        #pragma unroll
        for (int p = 0; p < 4; ++p) {
            int c = p * 16 + ty;
            int m4 = tx * 4;
            ushort4 u;
            u.x = f2b(T[c][m4 + 0]); u.y = f2b(T[c][m4 + 1]);
            u.z = f2b(T[c][m4 + 2]); u.w = f2b(T[c][m4 + 3]);
            *(ushort4*)(xT2 + ((long)t * 512 + b * 64 + c) * KA + m0 + m4) = u;
        }
    } else if (blk < 64624) {
        const int isData = (blk < 46192);
        const int base = isData ? 30832 : 46192;
        const int Tt = isData ? TD : T0D;
        const float* src = isData ? data : orig;
        ushort* dst = isData ? datab : origb;
        long i = (long)(blk - base) * 256 + tid; // quads: 8*Tt*3072*16
        long tot = 8L * Tt * NP * 16;
        if (i >= tot) return;
        int c4 = (int)(i & 15) * 4;
        long r = i >> 4;                 // (b*Tt+t)*3072 + n
        int n = (int)(r % NP);
        long bt = r / NP;
        ushort4 u = {0, 0, 0, 0};
        if (n < NN) {
            float4 v = *(const float4*)(src + (bt * NN + n) * 64 + c4);
            u.x = f2b(v.x); u.y = f2b(v.y); u.z = f2b(v.z); u.w = f2b(v.w);
        }
        *(ushort4*)(dst + r * 64 + c4) = u;
    } else {
        int i = (blk - 64624) * 256 + tid;
        if (i >= 128 * 512) return;
        int r = i >> 9, k = i & 511;
        int q = r >> 6, jp = r & 63;
        int o = (jp < 32) ? (q * 32 + jp) : (64 + q * 32 + (jp - 32));
        int s = k >> 6, c = k & 63;
        float v = (s < 3) ? c1w[(o * 64 + c) * 3 + s] : c2w[(o * 64 + c) * 5 + (s - 3)];
        wb[i] = f2b(v);
    }
}

// ---------------------------------------------------------------------------
// 256x256 8-wave phase-split GEMM (T2+T3+T4+T5 stack, 256^2 quadrant).
// Y[j][m] = sum_seg sum_k A_seg[j][k] * B[m][colOff_seg + k], K=3008=47*64/seg.
// BK=64 split into k-halves of 32; 4 phases per K-tile:
//   P0 (jh0,ks0): vmcnt(4)+bar; ds_read B(4)+A(4); issue A'kh0; 16 MFMA; bar
//   P1 (jh1,ks0): ds_read A(4);                    issue B'kh0; 16 MFMA; bar
//   P2 (jh0,ks1): vmcnt(4|0last)+bar; B(4)+A(4);   issue A'kh1; 16 MFMA; bar
//   P3 (jh1,ks1): ds_read A(4);                    issue B'kh1; 16 MFMA; bar
// k-half staging makes every wave's dependency uniform -> counted vmcnt(4)
// retires exactly the kh about to be read; loads span barriers (never drain
// to 0 mid-loop). Swizzle identical to R6-verified (conflicts 2.77e7 -> 0):
// write kseg' = (l&3)^((l>>3)&3); read slot = half^((rsub>>1)&3).
// LDS: A/B double-buffered 256x64 bf16 = 128 KB dynamic; 1 block/CU, 8 waves.
// ---------------------------------------------------------------------------
#define MFMA_BF16 __builtin_amdgcn_mfma_f32_16x16x32_bf16

__device__ __forceinline__ void gemm8_body(
    const ushort* __restrict__ A0, const ushort* __restrict__ A1, int nseg,
    const ushort* __restrict__ Badj, int colOff0, int colOff1,
    float* __restrict__ Yp, ushort* lds)
{
    const int m0 = blockIdx.x * 256;
    const int j0 = blockIdx.y * 256;
    const int tid = threadIdx.x;
    const int lane = tid & 63;
    const int wv = tid >> 6;                 // 0..7
    const int wjr = (wv >> 2) * 128;         // wave j-offset (2 rows of waves)
    const int wmr = (wv & 3) * 64;           // wave m-offset (4 cols of waves)
    const int half = (lane >> 4) & 3;
    const int rsub = lane & 15;
    const int hsw = (half ^ ((rsub >> 1) & 3)) * 8;
    const int kxs = ((lane & 3) ^ ((lane >> 3) & 3)) * 8;
    const int NT = 47 * nseg;

    ushort* sA0 = lds;
    ushort* sA1 = lds + 16384;
    ushort* sB0 = lds + 32768;
    ushort* sB1 = lds + 49152;

    floatx4 acc[8][4] = {};

    int offA[8], offB[4];
    #pragma unroll
    for (int i = 0; i < 8; ++i) offA[i] = (wjr + i * 16 + rsub) * 32 + hsw;
    #pragma unroll
    for (int j = 0; j < 4; ++j) offB[j] = (wmr + j * 16 + rsub) * 32 + hsw;

    const int dOff = wv * 1024;              // ushort units; +q*512, +h*8192

    const long rA = j0 + wv * 32 + (lane >> 2);
    const long rB = m0 + wv * 32 + (lane >> 2);
    const ushort* bA  = A0 + rA * KA + kxs;
    const ushort* bB  = Badj + colOff0 + rB * KB + kxs;
    const ushort* aA1 = A1 + rA * KA + kxs;
    const ushort* aB1 = Badj + colOff1 + rB * KB + kxs;
    int issued = 0;

    auto issueA = [&](ushort* dA, int h) {
        const ushort* g = bA + h * 32;
        ld_lds16(g,           dA + h * 8192 + dOff);
        ld_lds16(g + 16 * KA, dA + h * 8192 + 512 + dOff);
    };
    auto issueB = [&](ushort* dB, int h) {
        const ushort* g = bB + h * 32;
        ld_lds16(g,           dB + h * 8192 + dOff);
        ld_lds16(g + 16 * KB, dB + h * 8192 + 512 + dOff);
    };
    auto adv = [&]() {
        ++issued;
        if (issued == 47 && nseg == 2) { bA = aA1; bB = aB1; }
        else { bA += 64; bB += 64; }
    };

    // prologue: tile 0 fully issued into buf0 (8 loads outstanding)
    issueA(sA0, 0); issueB(sB0, 0); issueA(sA0, 1); issueB(sB0, 1); adv();

    for (int t = 0; t < NT; ++t) {
        ushort* cA = (t & 1) ? sA1 : sA0;
        ushort* cB = (t & 1) ? sB1 : sB0;
        ushort* nA = (t & 1) ? sA0 : sA1;
        ushort* nB = (t & 1) ? sB0 : sB1;
        const bool pre = (t + 1 < NT);
        short8 af[4], bf[4];

        // ---- P0: (jh0, ks0) -- needs cur kh0 (oldest 4 outstanding)
        asm volatile("s_waitcnt vmcnt(4)" ::: "memory");
        __builtin_amdgcn_s_barrier();
        __builtin_amdgcn_sched_barrier(0);
        #pragma unroll
        for (int j = 0; j < 4; ++j) bf[j] = *(const short8*)(cB + offB[j]);
        #pragma unroll
        for (int i = 0; i < 4; ++i) af[i] = *(const short8*)(cA + offA[i]);
        if (pre) issueA(nA, 0);
        __builtin_amdgcn_s_setprio(1);
        #pragma unroll
        for (int i = 0; i < 4; ++i)
            #pragma unroll
            for (int j = 0; j < 4; ++j)
                acc[i][j] = MFMA_BF16(af[i], bf[j], acc[i][j], 0, 0, 0);
        __builtin_amdgcn_s_setprio(0);
        __builtin_amdgcn_s_barrier();
        __builtin_amdgcn_sched_barrier(0);

        // ---- P1: (jh1, ks0) -- bf reused
        #pragma unroll
        for (int i = 0; i < 4; ++i) af[i] = *(const short8*)(cA + offA[4 + i]);
        if (pre) issueB(nB, 0);
        __builtin_amdgcn_s_setprio(1);
        #pragma unroll
        for (int i = 0; i < 4; ++i)
            #pragma unroll
            for (int j = 0; j < 4; ++j)
                acc[4 + i][j] = MFMA_BF16(af[i], bf[j], acc[4 + i][j], 0, 0, 0);
        __builtin_amdgcn_s_setprio(0);
        __builtin_amdgcn_s_barrier();
        __builtin_amdgcn_sched_barrier(0);

        // ---- P2: (jh0, ks1) -- needs cur kh1
        if (t == NT - 1) asm volatile("s_waitcnt vmcnt(0)" ::: "memory");
        else             asm volatile("s_waitcnt vmcnt(4)" ::: "memory");
        __builtin_amdgcn_s_barrier();
        __builtin_amdgcn_sched_barrier(0);
        #pragma unroll
        for (int j = 0; j < 4; ++j) bf[j] = *(const short8*)(cB + 8192 + offB[j]);
        #pragma unroll
        for (int i = 0; i < 4; ++i) af[i] = *(const short8*)(cA + 8192 + offA[i]);
        if (pre) issueA(nA, 1);
        __builtin_amdgcn_s_setprio(1);
        #pragma unroll
        for (int i = 0; i < 4; ++i)
            #pragma unroll
            for (int j = 0; j < 4; ++j)
                acc[i][j] = MFMA_BF16(af[i], bf[j], acc[i][j], 0, 0, 0);
        __builtin_amdgcn_s_setprio(0);
        __builtin_amdgcn_s_barrier();
        __builtin_amdgcn_sched_barrier(0);

        // ---- P3: (jh1, ks1)
        #pragma unroll
        for (int i = 0; i < 4; ++i) af[i] = *(const short8*)(cA + 8192 + offA[4 + i]);
        if (pre) { issueB(nB, 1); adv(); }
        __builtin_amdgcn_s_setprio(1);
        #pragma unroll
        for (int i = 0; i < 4; ++i)
            #pragma unroll
            for (int j = 0; j < 4; ++j)
                acc[4 + i][j] = MFMA_BF16(af[i], bf[j], acc[4 + i][j], 0, 0, 0);
        __builtin_amdgcn_s_setprio(0);
        __builtin_amdgcn_s_barrier();
        __builtin_amdgcn_sched_barrier(0);
    }

    #pragma unroll
    for (int i = 0; i < 8; ++i) {
        int jrow = j0 + wjr + i * 16 + half * 4;
        #pragma unroll
        for (int j = 0; j < 4; ++j) {
            int mcol = m0 + wmr + j * 16 + rsub;
            float* o = Yp + (long)jrow * MY + mcol;
            o[0L * MY] = acc[i][j].x;
            o[1L * MY] = acc[i][j].y;
            o[2L * MY] = acc[i][j].z;
            o[3L * MY] = acc[i][j].w;
        }
    }
}

// Generic per-w wrapper (d1/d2): grid (12, 2, 8), 512 thr, 128 KB dyn LDS
__global__ __launch_bounds__(512, 2) void gemm_mfma(
    const ushort* __restrict__ A0, const ushort* __restrict__ A1, int nseg, long aW,
    const ushort* __restrict__ Badj, int colOff0, int colOff1,
    float* __restrict__ Y)
{
    extern __shared__ ushort dynlds[];
    const int w = blockIdx.z;
    gemm8_body(A0 + (long)w * aW, A1 + (long)w * aW, nseg,
               Badj, colOff0, colOff1, Y + (long)w * YSLAB, dynlds);
}

// Combined wing + d0: grid (12, 2, 16): z<8 wing (nseg=2), z>=8 d0 (nseg=1).
__global__ __launch_bounds__(512, 2) void gemm_wing_d0(
    const ushort* __restrict__ xT2, const ushort* __restrict__ Badj,
    float* __restrict__ ywing, float* __restrict__ yd)
{
    extern __shared__ ushort dynlds[];
    const int zz = blockIdx.z;
    if (zz < 8) {
        gemm8_body(xT2 + (long)zz * TSLAB, xT2 + (long)(zz + 1) * TSLAB, 2,
                   Badj, 0, 3000, ywing + (long)zz * YSLAB, dynlds);
    } else {
        const int w = zz - 8;
        const ushort* a = xT2 + (long)(w + 2) * TSLAB;
        gemm8_body(a, a, 1, Badj, 6000, 0, yd + (long)w * YSLAB, dynlds);
    }
}

// Gated convs via MFMA with the verified 3-stage counted-vmcnt pipeline.
__global__ __launch_bounds__(256) void conv_mfma(
    const ushort* __restrict__ datab, const ushort* __restrict__ origb,
    const ushort* __restrict__ wb,
    const float* __restrict__ b1, const float* __restrict__ b2,
    float* __restrict__ out)
{
    const int b = blockIdx.y >> 3, wt = blockIdx.y & 7;
    const int n0 = blockIdx.x * 128;
    const int tid = threadIdx.x;
    const int lane = tid & 63;
    const int wv = tid >> 6;
    __shared__ ushort shA[3][4096];
    __shared__ ushort shB[3][4096];
    floatx4 acc1[4][4] = {};
    floatx4 acc2[4][4] = {};
    const int srow = wv * 16 + (lane >> 2);
    const int kswz = ((lane & 3) ^ ((lane >> 3) & 3)) * 8;
    const int wj = (wv >> 1) * 64, wm = (wv & 1) * 64;
    const int half = lane >> 4;
    const int rsub = lane & 15;
    const int hsw  = (half ^ ((rsub >> 1) & 3)) * 8;
    const int wOff = wv * 512;

    int offA[4], offB[4];
    #pragma unroll
    for (int i = 0; i < 4; ++i) {
        offA[i] = (wj + i * 16 + rsub) * 32 + hsw;
        offB[i] = (wm + i * 16 + rsub) * 32 + hsw;
    }

    auto stage = [&](int kt, ushort* dA, ushort* dB) {
        const int sl = kt >> 1, koff = (kt & 1) * 32;
        const ushort* Ab = (sl < 3) ? datab + (long)(b * TD + wt + sl) * NP * 64
                                    : origb + (long)(b * T0D + wt + (sl - 3)) * NP * 64;
        const ushort* gA = Ab + (long)(n0 + srow) * 64 + koff + kswz;
        ld_lds16(gA,           dA + wOff);
        ld_lds16(gA + 64 * 64, dA + 2048 + wOff);
        const ushort* gB = wb + (long)srow * 512 + kt * 32 + kswz;
        ld_lds16(gB,            dB + wOff);
        ld_lds16(gB + 64 * 512, dB + 2048 + wOff);
    };

    ushort *pA0 = shA[0], *pA1 = shA[1], *pA2 = shA[2];
    ushort *pB0 = shB[0], *pB1 = shB[1], *pB2 = shB[2];

    stage(0, pA0, pB0);
    stage(1, pA1, pB1);
    asm volatile("s_waitcnt vmcnt(4)" ::: "memory");
    __builtin_amdgcn_s_barrier();
    __builtin_amdgcn_sched_barrier(0);

    for (int s = 0; s < 16; ++s) {
        if (s + 2 < 16)
            stage(s + 2, pA2, pB2);
        short8 af[4], bf[4];
        #pragma unroll
        for (int i = 0; i < 4; ++i)
            af[i] = *(const short8*)(pA0 + offA[i]);
        #pragma unroll
        for (int i = 0; i < 4; ++i)
            bf[i] = *(const short8*)(pB0 + offB[i]);
        if (s < 6) {
            #pragma unroll
            for (int i = 0; i < 4; ++i)
                #pragma unroll
                for (int jj = 0; jj < 4; ++jj)
                    acc1[i][jj] = MFMA_BF16(af[i], bf[jj], acc1[i][jj], 0, 0, 0);
        } else {
            #pragma unroll
            for (int i = 0; i < 4; ++i)
                #pragma unroll
                for (int jj = 0; jj < 4; ++jj)
                    acc2[i][jj] = MFMA_BF16(af[i], bf[jj], acc2[i][jj], 0, 0, 0);
        }
        if (s + 2 < 16) {
            asm volatile("s_waitcnt vmcnt(4)" ::: "memory");
        } else if (s + 1 < 16) {
            asm volatile("s_waitcnt vmcnt(0)" ::: "memory");
        }
        __builtin_amdgcn_s_barrier();
        __builtin_amdgcn_sched_barrier(0);
        ushort* t;
        t = pA0; pA0 = pA1; pA1 = pA2; pA2 = t;
        t = pB0; pB0 = pB1; pB1 = pB2; pB2 = t;
    }

    const int q = wv & 1;
    float* outp = out + (long)(b * WD + wt) * NN * 64;
    #pragma unroll
    for (int i = 0; i < 4; ++i) {
        const int nbase = n0 + wj + i * 16 + half * 4;
        #pragma unroll
        for (int jj = 0; jj < 2; ++jj) {
            const int ol = q * 32 + jj * 16 + rsub;
            const float bl1 = b1[ol], br1 = b1[64 + ol];
            const float bl2 = b2[ol], br2 = b2[64 + ol];
            float zl1[4] = {acc1[i][jj].x, acc1[i][jj].y, acc1[i][jj].z, acc1[i][jj].w};
            float zr1[4] = {acc1[i][jj+2].x, acc1[i][jj+2].y, acc1[i][jj+2].z, acc1[i][jj+2].w};
            float zl2[4] = {acc2[i][jj].x, acc2[i][jj].y, acc2[i][jj].z, acc2[i][jj].w};
            float zr2[4] = {acc2[i][jj+2].x, acc2[i][jj+2].y, acc2[i][jj+2].z, acc2[i][jj+2].w};
            #pragma unroll
            for (int r = 0; r < 4; ++r) {
                int n = nbase + r;
                if (n < NN) {
                    float ov = sigm(zl1[r] + bl1) * (zr1[r] + br1)
                             + sigm(zl2[r] + bl2) * (zr2[r] + br2);
                    outp[(long)n * 64 + ol] = ov;
                }
            }
        }
    }
}

// GLU in transposed space, b split across blockIdx.z.
__global__ __launch_bounds__(256) void glu_t(
    const float* __restrict__ Yd, const float* __restrict__ Ywing,
    const float* __restrict__ gw_all, const float* __restrict__ gb_all,
    int kIdx, ushort* __restrict__ dp, float* __restrict__ maxd)
{
    const int w = blockIdx.y;
    const int b = blockIdx.z;
    const int m0 = blockIdx.x * 64;
    const int tid = threadIdx.x;
    const int tx = tid & 15, ty = tid >> 4;
    const float* Ydp = Yd + (long)w * YSLAB;
    const float* Ywp = Ywing + (long)w * YSLAB;
    ushort* dpp = dp + (long)w * TSLAB;
    float* mdp = maxd + (long)w * MSLAB;
    const float* gw = gw_all + (long)(w * 3 + kIdx) * 8192;
    const float* gb = gb_all + (w * 3 + kIdx) * 128;
    __shared__ float gws[64][132];
    __shared__ float Ys[64][68];
    #pragma unroll
    for (int p = 0; p < 8; ++p) {
        int r = p * 8 + (tid >> 5);
        int c0 = (tid & 31) * 4;
        *(float4*)&gws[r][c0] = *(const float4*)(gw + r * 128 + c0);
    }
    #pragma unroll
    for (int p = 0; p < 4; ++p) {
        int c = p * 16 + ty;
        long off = (long)(b * 64 + c) * MY + m0 + tx * 4;
        float4 v1 = *(const float4*)(Ydp + off);
        float4 v2 = *(const float4*)(Ywp + off);
        Ys[c][tx * 4 + 0] = v1.x + v2.x;
        Ys[c][tx * 4 + 1] = v1.y + v2.y;
        Ys[c][tx * 4 + 2] = v1.z + v2.z;
        Ys[c][tx * 4 + 3] = v1.w + v2.w;
    }
    __syncthreads();
    float acc[8][4] = {{0.f}};
    for (int c = 0; c < 64; ++c) {
        float4 ym = *(const float4*)&Ys[c][tx * 4];
        #pragma unroll
        for (int p = 0; p < 8; ++p) {
            float a = gws[c][ty + p * 16];
            acc[p][0] = fmaf(a, ym.x, acc[p][0]);
            acc[p][1] = fmaf(a, ym.y, acc[p][1]);
            acc[p][2] = fmaf(a, ym.z, acc[p][2]);
            acc[p][3] = fmaf(a, ym.w, acc[p][3]);
        }
    }
    #pragma unroll
    for (int p = 0; p < 4; ++p) {
        int c = ty + p * 16;
        float bl = gb[c], br = gb[64 + c];
        long row = (long)(b * 64 + c) * KA + m0 + tx * 4;
        float d[4];
        #pragma unroll
        for (int q = 0; q < 4; ++q) {
            float zl = acc[p][q] + bl;
            float zr = acc[p + 4][q] + br;
            d[q] = zl * sigm(zr);
        }
        int mb = m0 + tx * 4;
        if (kIdx < 2) {
            ushort4 u;
            u.x = (mb + 0 < NN) ? f2b(d[0]) : (ushort)0;
            u.y = (mb + 1 < NN) ? f2b(d[1]) : (ushort)0;
            u.z = (mb + 2 < NN) ? f2b(d[2]) : (ushort)0;
            u.w = (mb + 3 < NN) ? f2b(d[3]) : (ushort)0;
            *(ushort4*)(dpp + row) = u;
        }
        if (kIdx == 0) {
            float4 m4 = {d[0], d[1], d[2], d[3]};
            *(float4*)(mdp + row) = m4;
        } else {
            float4 old = *(const float4*)(mdp + row);
            float4 m4;
            m4.x = fmaxf(old.x, d[0]); m4.y = fmaxf(old.y, d[1]);
            m4.z = fmaxf(old.z, d[2]); m4.w = fmaxf(old.w, d[3]);
            *(float4*)(mdp + row) = m4;
        }
    }
}

// out[b][w][n][c] += maxd[w][b*64+c][n] (LDS transpose) + (data+temb+semb)[b][w+2][n][c]
__global__ __launch_bounds__(256) void final_t(
    const float* __restrict__ maxd, const float* __restrict__ data,
    const float* __restrict__ temb, const float* __restrict__ semb,
    float* __restrict__ out)
{
    const int w = blockIdx.z, b = blockIdx.y;
    const int m0 = blockIdx.x * 64;
    const int tid = threadIdx.x;
    const int tx = tid & 15, ty = tid >> 4;
    const float* mdp = maxd + (long)w * MSLAB;
    __shared__ float T[64][68];
    #pragma unroll
    for (int p = 0; p < 4; ++p) {
        int c = p * 16 + ty;
        float4 v = *(const float4*)(mdp + (long)(b * 64 + c) * KA + m0 + tx * 4);
        T[c][tx * 4 + 0] = v.x; T[c][tx * 4 + 1] = v.y;
        T[c][tx * 4 + 2] = v.z; T[c][tx * 4 + 3] = v.w;
    }
    __syncthreads();
    #pragma unroll
    for (int p = 0; p < 4; ++p) {
        int nl = p * 16 + ty;
        int n = m0 + nl;
        if (n < NN) {
            int c4 = tx * 4;
            long oidx = ((long)(b * WD + w) * NN + n) * 64 + c4;
            float4 o  = *(const float4*)(out + oidx);
            float4 dd = *(const float4*)(data + ((long)(b * TD + w + 2) * NN + n) * 64 + c4);
            float4 tv = *(const float4*)(temb + (w + 2) * 64 + c4);
            float4 sv = *(const float4*)(semb + n * 64 + c4);
            o.x += T[c4 + 0][nl] + dd.x + tv.x + sv.x;
            o.y += T[c4 + 1][nl] + dd.y + tv.y + sv.y;
            o.z += T[c4 + 2][nl] + dd.z + tv.z + sv.z;
            o.w += T[c4 + 3][nl] + dd.w + tv.w + sv.w;
            *(float4*)(out + oidx) = o;
        }
    }
}

extern "C" void kernel_launch(void* const* d_in, const int* in_sizes, int n_in,
                              void* d_out, int out_size, void* d_ws, size_t ws_size,
                              hipStream_t stream) {
    const float* orig = (const float*)d_in[0];
    const float* data = (const float*)d_in[1];
    const float* adj  = (const float*)d_in[2];
    const float* c1w  = (const float*)d_in[3];
    const float* c1b  = (const float*)d_in[4];
    const float* c2w  = (const float*)d_in[5];
    const float* c2b  = (const float*)d_in[6];
    const float* temb = (const float*)d_in[7];
    const float* semb = (const float*)d_in[8];
    const float* gw   = (const float*)d_in[9];
    const float* gb   = (const float*)d_in[10];
    float* out = (float*)d_out;

    // One-time opt-in for 128 KB dynamic LDS (host-side attribute set; no
    // stream ops -> graph-capture safe; idempotent).
    static bool ldsAttrSet = false;
    if (!ldsAttrSet) {
        hipFuncSetAttribute((const void*)gemm_wing_d0,
                            hipFuncAttributeMaxDynamicSharedMemorySize, 131072);
        hipFuncSetAttribute((const void*)gemm_mfma,
                            hipFuncAttributeMaxDynamicSharedMemorySize, 131072);
        ldsAttrSet = true;
    }

    char* ws = (char*)d_ws;
    ushort* adjb = (ushort*)ws;                          ws += 3072L * 9024 * 2;   // 55.44 MB
    ushort* xT2  = (ushort*)ws;                          ws += 10L * TSLAB * 2;    // 30.80 MB
    ushort* dpb  = (ushort*)ws;                          ws += 8L * TSLAB * 2;     // 24.64 MB
    float*  ywing = (float*)ws;                          ws += 8L * YSLAB * 4;     // 50.33 MB
    float*  yd    = (float*)ws;                          ws += 8L * YSLAB * 4;     // 50.33 MB
    float*  maxd  = (float*)ws;                          // 49.28 MB  (total ~260.8 MB)

    // Aliases (dead until overwritten by later kernels, in-stream order):
    ushort* wb    = (ushort*)ywing;   // 128 KB, consumed by conv_mfma before wing gemm
    ushort* datab = (ushort*)yd;      // 31.5 MB, consumed before d0 gemm writes yd
    ushort* origb = (ushort*)maxd;    // 37.7 MB, consumed before glu_t writes maxd

    prep_all<<<dim3(64880), 256, 0, stream>>>(adj, data, orig, temb, semb, c1w, c2w,
                                              adjb, xT2, datab, origb, wb);

    conv_mfma<<<dim3(24, 64), 256, 0, stream>>>(datab, origb, wb, c1b, c2b, out);

    // wing + d0 combined, 256^2 8-wave phase-split GEMM (128 KB dynamic LDS)
    gemm_wing_d0<<<dim3(12, 2, 16), 512, 131072, stream>>>(xT2, adjb, ywing, yd);
    glu_t<<<dim3(47, 8, 8), 256, 0, stream>>>(yd, ywing, gw, gb, 0, dpb, maxd);
    gemm_mfma<<<dim3(12, 2, 8), 512, 131072, stream>>>(dpb, dpb, 1, TSLAB, adjb, 6000, 0, yd);
    glu_t<<<dim3(47, 8, 8), 256, 0, stream>>>(yd, ywing, gw, gb, 1, dpb, maxd);
    gemm_mfma<<<dim3(12, 2, 8), 512, 131072, stream>>>(dpb, dpb, 1, TSLAB, adjb, 6000, 0, yd);
    glu_t<<<dim3(47, 8, 8), 256, 0, stream>>>(yd, ywing, gw, gb, 2, dpb, maxd);

    final_t<<<dim3(47, 8, 8), 256, 0, stream>>>(maxd, data, temb, semb, out);
}

// Round 14
// 938.199 us; speedup vs baseline: 1.2291x; 1.0251x over previous
//
#include <hip/hip_runtime.h>
#include <hip/hip_bf16.h>
#include <math.h>

#define NN 3000
#define NP 3072          // padded node dim
#define KA 3008          // A-operand row stride (bf16 elems), k=node padded
#define KB 9024          // adj bf16 row stride
#define MY 3072          // Y fp32 row stride (padded node dim)
#define BD 8
#define TD 10
#define T0D 12
#define WD 8
#define TSLAB (512L*KA)  // bf16 elems per t-slab / d' slab
#define YSLAB (512L*MY)  // fp32 elems per Y slab
#define MSLAB (512L*KA)  // fp32 elems per maxd slab

typedef __attribute__((ext_vector_type(8))) short short8;
typedef __attribute__((ext_vector_type(4))) float floatx4;

__device__ __forceinline__ float sigm(float x) { return 1.0f / (1.0f + __expf(-x)); }
__device__ __forceinline__ ushort f2b(float f) {
    __hip_bfloat16 h = __float2bfloat16(f);
    return *reinterpret_cast<ushort*>(&h);
}
__device__ __forceinline__ void ld_lds16(const void* g, void* l) {
    __builtin_amdgcn_global_load_lds((const __attribute__((address_space(1))) unsigned int*)g,
                                     (__attribute__((address_space(3))) unsigned int*)l, 16, 0, 0);
}

// Fused prep. Block ranges:
//   [0, 27072)       adj  (3000x9000 f32 -> 3072x9024 bf16, pads zero)
//   [27072, 30832)   xt   (xT2 transposed; ALSO emits datab bf16 in load loop)
//   [30832, 49264)   db(orig, T0D)
//   [49264, 49520)   wb   (conv weight permute+pack)
// datab rows [3008,3072) stay uninitialized: only consumed as conv A-rows for
// discarded outputs (n>=3000 never written) -- harmless.
__global__ __launch_bounds__(256) void prep_all(
    const float* __restrict__ adj, const float* __restrict__ data,
    const float* __restrict__ orig, const float* __restrict__ temb,
    const float* __restrict__ semb, const float* __restrict__ c1w,
    const float* __restrict__ c2w,
    ushort* __restrict__ adjb, ushort* __restrict__ xT2,
    ushort* __restrict__ datab, ushort* __restrict__ origb,
    ushort* __restrict__ wb)
{
    const int blk = blockIdx.x;
    const int tid = threadIdx.x;
    __shared__ float T[64][68];

    if (blk < 27072) {
        long i = (long)blk * 256 + tid;          // 3072*2256 quads
        if (i >= 3072L * 2256) return;
        int r  = (int)(i / 2256);
        int c4 = (int)(i % 2256) * 4;
        ushort4 u = {0, 0, 0, 0};
        if (r < NN && c4 < 9000) {
            float4 v = *(const float4*)(adj + (long)r * 9000 + c4);
            u.x = f2b(v.x); u.y = f2b(v.y); u.z = f2b(v.z); u.w = f2b(v.w);
        }
        *(ushort4*)(adjb + (long)r * KB + c4) = u;
    } else if (blk < 30832) {
        int id = blk - 27072;                    // x + 47*(b + 8*t)
        const int x = id % 47;  id /= 47;
        const int b = id & 7;
        const int t = id >> 3;
        const int m0 = x * 64;
        const int tx = tid & 15, ty = tid >> 4;
        #pragma unroll
        for (int p = 0; p < 4; ++p) {
            int nl = p * 16 + ty;
            int n = m0 + nl;
            int c4 = tx * 4;
            float4 v = {0.f, 0.f, 0.f, 0.f};
            ushort4 du = {0, 0, 0, 0};
            if (n < NN) {
                float4 dv = *(const float4*)(data + ((long)(b * TD + t) * NN + n) * 64 + c4);
                float4 tv = *(const float4*)(temb + t * 64 + c4);
                float4 sv = *(const float4*)(semb + n * 64 + c4);
                du.x = f2b(dv.x); du.y = f2b(dv.y); du.z = f2b(dv.z); du.w = f2b(dv.w);
                v.x = dv.x + tv.x + sv.x; v.y = dv.y + tv.y + sv.y;
                v.z = dv.z + tv.z + sv.z; v.w = dv.w + tv.w + sv.w;
            }
            *(ushort4*)(datab + ((long)(b * TD + t) * NP + n) * 64 + c4) = du;
            T[c4 + 0][nl] = v.x; T[c4 + 1][nl] = v.y;
            T[c4 + 2][nl] = v.z; T[c4 + 3][nl] = v.w;
        }
        __syncthreads();
        #pragma unroll
        for (int p = 0; p < 4; ++p) {
            int c = p * 16 + ty;
            int m4 = tx * 4;
            ushort4 u;
            u.x = f2b(T[c][m4 + 0]); u.y = f2b(T[c][m4 + 1]);
            u.z = f2b(T[c][m4 + 2]); u.w = f2b(T[c][m4 + 3]);
            *(ushort4*)(xT2 + ((long)t * 512 + b * 64 + c) * KA + m0 + m4) = u;
        }
    } else if (blk < 49264) {
        long i = (long)(blk - 30832) * 256 + tid; // quads: 8*T0D*3072*16
        long tot = 8L * T0D * NP * 16;
        if (i >= tot) return;
        int c4 = (int)(i & 15) * 4;
        long r = i >> 4;                 // (b*T0D+t)*3072 + n
        int n = (int)(r % NP);
        long bt = r / NP;
        ushort4 u = {0, 0, 0, 0};
        if (n < NN) {
            float4 v = *(const float4*)(orig + (bt * NN + n) * 64 + c4);
            u.x = f2b(v.x); u.y = f2b(v.y); u.z = f2b(v.z); u.w = f2b(v.w);
        }
        *(ushort4*)(origb + r * 64 + c4) = u;
    } else {
        int i = (blk - 49264) * 256 + tid;
        if (i >= 128 * 512) return;
        int r = i >> 9, k = i & 511;
        int q = r >> 6, jp = r & 63;
        int o = (jp < 32) ? (q * 32 + jp) : (64 + q * 32 + (jp - 32));
        int s = k >> 6, c = k & 63;
        float v = (s < 3) ? c1w[(o * 64 + c) * 3 + s] : c2w[(o * 64 + c) * 5 + (s - 3)];
        wb[i] = f2b(v);
    }
}

// ---------------------------------------------------------------------------
// 256x256 8-wave phase-split GEMM (verified R11: 264us, MfmaUtil 37%, 0 confl)
// ---------------------------------------------------------------------------
#define MFMA_BF16 __builtin_amdgcn_mfma_f32_16x16x32_bf16

__device__ __forceinline__ void gemm8_body(
    const ushort* __restrict__ A0, const ushort* __restrict__ A1, int nseg,
    const ushort* __restrict__ Badj, int colOff0, int colOff1,
    float* __restrict__ Yp, ushort* lds)
{
    const int m0 = blockIdx.x * 256;
    const int j0 = blockIdx.y * 256;
    const int tid = threadIdx.x;
    const int lane = tid & 63;
    const int wv = tid >> 6;                 // 0..7
    const int wjr = (wv >> 2) * 128;         // wave j-offset (2 rows of waves)
    const int wmr = (wv & 3) * 64;           // wave m-offset (4 cols of waves)
    const int half = (lane >> 4) & 3;
    const int rsub = lane & 15;
    const int hsw = (half ^ ((rsub >> 1) & 3)) * 8;
    const int kxs = ((lane & 3) ^ ((lane >> 3) & 3)) * 8;
    const int NT = 47 * nseg;

    ushort* sA0 = lds;
    ushort* sA1 = lds + 16384;
    ushort* sB0 = lds + 32768;
    ushort* sB1 = lds + 49152;

    floatx4 acc[8][4] = {};

    int offA[8], offB[4];
    #pragma unroll
    for (int i = 0; i < 8; ++i) offA[i] = (wjr + i * 16 + rsub) * 32 + hsw;
    #pragma unroll
    for (int j = 0; j < 4; ++j) offB[j] = (wmr + j * 16 + rsub) * 32 + hsw;

    const int dOff = wv * 1024;              // ushort units; +q*512, +h*8192

    const long rA = j0 + wv * 32 + (lane >> 2);
    const long rB = m0 + wv * 32 + (lane >> 2);
    const ushort* bA  = A0 + rA * KA + kxs;
    const ushort* bB  = Badj + colOff0 + rB * KB + kxs;
    const ushort* aA1 = A1 + rA * KA + kxs;
    const ushort* aB1 = Badj + colOff1 + rB * KB + kxs;
    int issued = 0;

    auto issueA = [&](ushort* dA, int h) {
        const ushort* g = bA + h * 32;
        ld_lds16(g,           dA + h * 8192 + dOff);
        ld_lds16(g + 16 * KA, dA + h * 8192 + 512 + dOff);
    };
    auto issueB = [&](ushort* dB, int h) {
        const ushort* g = bB + h * 32;
        ld_lds16(g,           dB + h * 8192 + dOff);
        ld_lds16(g + 16 * KB, dB + h * 8192 + 512 + dOff);
    };
    auto adv = [&]() {
        ++issued;
        if (issued == 47 && nseg == 2) { bA = aA1; bB = aB1; }
        else { bA += 64; bB += 64; }
    };

    // prologue: tile 0 fully issued into buf0 (8 loads outstanding)
    issueA(sA0, 0); issueB(sB0, 0); issueA(sA0, 1); issueB(sB0, 1); adv();

    for (int t = 0; t < NT; ++t) {
        ushort* cA = (t & 1) ? sA1 : sA0;
        ushort* cB = (t & 1) ? sB1 : sB0;
        ushort* nA = (t & 1) ? sA0 : sA1;
        ushort* nB = (t & 1) ? sB0 : sB1;
        const bool pre = (t + 1 < NT);
        short8 af[4], bf[4];

        // ---- P0: (jh0, ks0) -- needs cur kh0 (oldest 4 outstanding)
        asm volatile("s_waitcnt vmcnt(4)" ::: "memory");
        __builtin_amdgcn_s_barrier();
        __builtin_amdgcn_sched_barrier(0);
        #pragma unroll
        for (int j = 0; j < 4; ++j) bf[j] = *(const short8*)(cB + offB[j]);
        #pragma unroll
        for (int i = 0; i < 4; ++i) af[i] = *(const short8*)(cA + offA[i]);
        if (pre) issueA(nA, 0);
        __builtin_amdgcn_s_setprio(1);
        #pragma unroll
        for (int i = 0; i < 4; ++i)
            #pragma unroll
            for (int j = 0; j < 4; ++j)
                acc[i][j] = MFMA_BF16(af[i], bf[j], acc[i][j], 0, 0, 0);
        __builtin_amdgcn_s_setprio(0);
        __builtin_amdgcn_s_barrier();
        __builtin_amdgcn_sched_barrier(0);

        // ---- P1: (jh1, ks0) -- bf reused
        #pragma unroll
        for (int i = 0; i < 4; ++i) af[i] = *(const short8*)(cA + offA[4 + i]);
        if (pre) issueB(nB, 0);
        __builtin_amdgcn_s_setprio(1);
        #pragma unroll
        for (int i = 0; i < 4; ++i)
            #pragma unroll
            for (int j = 0; j < 4; ++j)
                acc[4 + i][j] = MFMA_BF16(af[i], bf[j], acc[4 + i][j], 0, 0, 0);
        __builtin_amdgcn_s_setprio(0);
        __builtin_amdgcn_s_barrier();
        __builtin_amdgcn_sched_barrier(0);

        // ---- P2: (jh0, ks1) -- needs cur kh1
        if (t == NT - 1) asm volatile("s_waitcnt vmcnt(0)" ::: "memory");
        else             asm volatile("s_waitcnt vmcnt(4)" ::: "memory");
        __builtin_amdgcn_s_barrier();
        __builtin_amdgcn_sched_barrier(0);
        #pragma unroll
        for (int j = 0; j < 4; ++j) bf[j] = *(const short8*)(cB + 8192 + offB[j]);
        #pragma unroll
        for (int i = 0; i < 4; ++i) af[i] = *(const short8*)(cA + 8192 + offA[i]);
        if (pre) issueA(nA, 1);
        __builtin_amdgcn_s_setprio(1);
        #pragma unroll
        for (int i = 0; i < 4; ++i)
            #pragma unroll
            for (int j = 0; j < 4; ++j)
                acc[i][j] = MFMA_BF16(af[i], bf[j], acc[i][j], 0, 0, 0);
        __builtin_amdgcn_s_setprio(0);
        __builtin_amdgcn_s_barrier();
        __builtin_amdgcn_sched_barrier(0);

        // ---- P3: (jh1, ks1)
        #pragma unroll
        for (int i = 0; i < 4; ++i) af[i] = *(const short8*)(cA + 8192 + offA[4 + i]);
        if (pre) { issueB(nB, 1); adv(); }
        __builtin_amdgcn_s_setprio(1);
        #pragma unroll
        for (int i = 0; i < 4; ++i)
            #pragma unroll
            for (int j = 0; j < 4; ++j)
                acc[4 + i][j] = MFMA_BF16(af[i], bf[j], acc[4 + i][j], 0, 0, 0);
        __builtin_amdgcn_s_setprio(0);
        __builtin_amdgcn_s_barrier();
        __builtin_amdgcn_sched_barrier(0);
    }

    #pragma unroll
    for (int i = 0; i < 8; ++i) {
        int jrow = j0 + wjr + i * 16 + half * 4;
        #pragma unroll
        for (int j = 0; j < 4; ++j) {
            int mcol = m0 + wmr + j * 16 + rsub;
            float* o = Yp + (long)jrow * MY + mcol;
            o[0L * MY] = acc[i][j].x;
            o[1L * MY] = acc[i][j].y;
            o[2L * MY] = acc[i][j].z;
            o[3L * MY] = acc[i][j].w;
        }
    }
}

// Generic per-w wrapper (d1/d2): grid (12, 2, 8), 512 thr, 128 KB dyn LDS
__global__ __launch_bounds__(512, 2) void gemm_mfma(
    const ushort* __restrict__ A0, const ushort* __restrict__ A1, int nseg, long aW,
    const ushort* __restrict__ Badj, int colOff0, int colOff1,
    float* __restrict__ Y)
{
    extern __shared__ ushort dynlds[];
    const int w = blockIdx.z;
    gemm8_body(A0 + (long)w * aW, A1 + (long)w * aW, nseg,
               Badj, colOff0, colOff1, Y + (long)w * YSLAB, dynlds);
}

// Combined wing + d0: grid (12, 2, 16): z<8 wing (nseg=2), z>=8 d0 (nseg=1).
__global__ __launch_bounds__(512, 2) void gemm_wing_d0(
    const ushort* __restrict__ xT2, const ushort* __restrict__ Badj,
    float* __restrict__ ywing, float* __restrict__ yd)
{
    extern __shared__ ushort dynlds[];
    const int zz = blockIdx.z;
    if (zz < 8) {
        gemm8_body(xT2 + (long)zz * TSLAB, xT2 + (long)(zz + 1) * TSLAB, 2,
                   Badj, 0, 3000, ywing + (long)zz * YSLAB, dynlds);
    } else {
        const int w = zz - 8;
        const ushort* a = xT2 + (long)(w + 2) * TSLAB;
        gemm8_body(a, a, 1, Badj, 6000, 0, yd + (long)w * YSLAB, dynlds);
    }
}

// Gated convs via MFMA with the verified 3-stage counted-vmcnt pipeline.
__global__ __launch_bounds__(256) void conv_mfma(
    const ushort* __restrict__ datab, const ushort* __restrict__ origb,
    const ushort* __restrict__ wb,
    const float* __restrict__ b1, const float* __restrict__ b2,
    float* __restrict__ out)
{
    const int b = blockIdx.y >> 3, wt = blockIdx.y & 7;
    const int n0 = blockIdx.x * 128;
    const int tid = threadIdx.x;
    const int lane = tid & 63;
    const int wv = tid >> 6;
    __shared__ ushort shA[3][4096];
    __shared__ ushort shB[3][4096];
    floatx4 acc1[4][4] = {};
    floatx4 acc2[4][4] = {};
    const int srow = wv * 16 + (lane >> 2);
    const int kswz = ((lane & 3) ^ ((lane >> 3) & 3)) * 8;
    const int wj = (wv >> 1) * 64, wm = (wv & 1) * 64;
    const int half = lane >> 4;
    const int rsub = lane & 15;
    const int hsw  = (half ^ ((rsub >> 1) & 3)) * 8;
    const int wOff = wv * 512;

    int offA[4], offB[4];
    #pragma unroll
    for (int i = 0; i < 4; ++i) {
        offA[i] = (wj + i * 16 + rsub) * 32 + hsw;
        offB[i] = (wm + i * 16 + rsub) * 32 + hsw;
    }

    auto stage = [&](int kt, ushort* dA, ushort* dB) {
        const int sl = kt >> 1, koff = (kt & 1) * 32;
        const ushort* Ab = (sl < 3) ? datab + (long)(b * TD + wt + sl) * NP * 64
                                    : origb + (long)(b * T0D + wt + (sl - 3)) * NP * 64;
        const ushort* gA = Ab + (long)(n0 + srow) * 64 + koff + kswz;
        ld_lds16(gA,           dA + wOff);
        ld_lds16(gA + 64 * 64, dA + 2048 + wOff);
        const ushort* gB = wb + (long)srow * 512 + kt * 32 + kswz;
        ld_lds16(gB,            dB + wOff);
        ld_lds16(gB + 64 * 512, dB + 2048 + wOff);
    };

    ushort *pA0 = shA[0], *pA1 = shA[1], *pA2 = shA[2];
    ushort *pB0 = shB[0], *pB1 = shB[1], *pB2 = shB[2];

    stage(0, pA0, pB0);
    stage(1, pA1, pB1);
    asm volatile("s_waitcnt vmcnt(4)" ::: "memory");
    __builtin_amdgcn_s_barrier();
    __builtin_amdgcn_sched_barrier(0);

    for (int s = 0; s < 16; ++s) {
        if (s + 2 < 16)
            stage(s + 2, pA2, pB2);
        short8 af[4], bf[4];
        #pragma unroll
        for (int i = 0; i < 4; ++i)
            af[i] = *(const short8*)(pA0 + offA[i]);
        #pragma unroll
        for (int i = 0; i < 4; ++i)
            bf[i] = *(const short8*)(pB0 + offB[i]);
        if (s < 6) {
            #pragma unroll
            for (int i = 0; i < 4; ++i)
                #pragma unroll
                for (int jj = 0; jj < 4; ++jj)
                    acc1[i][jj] = MFMA_BF16(af[i], bf[jj], acc1[i][jj], 0, 0, 0);
        } else {
            #pragma unroll
            for (int i = 0; i < 4; ++i)
                #pragma unroll
                for (int jj = 0; jj < 4; ++jj)
                    acc2[i][jj] = MFMA_BF16(af[i], bf[jj], acc2[i][jj], 0, 0, 0);
        }
        if (s + 2 < 16) {
            asm volatile("s_waitcnt vmcnt(4)" ::: "memory");
        } else if (s + 1 < 16) {
            asm volatile("s_waitcnt vmcnt(0)" ::: "memory");
        }
        __builtin_amdgcn_s_barrier();
        __builtin_amdgcn_sched_barrier(0);
        ushort* t;
        t = pA0; pA0 = pA1; pA1 = pA2; pA2 = t;
        t = pB0; pB0 = pB1; pB1 = pB2; pB2 = t;
    }

    const int q = wv & 1;
    float* outp = out + (long)(b * WD + wt) * NN * 64;
    #pragma unroll
    for (int i = 0; i < 4; ++i) {
        const int nbase = n0 + wj + i * 16 + half * 4;
        #pragma unroll
        for (int jj = 0; jj < 2; ++jj) {
            const int ol = q * 32 + jj * 16 + rsub;
            const float bl1 = b1[ol], br1 = b1[64 + ol];
            const float bl2 = b2[ol], br2 = b2[64 + ol];
            float zl1[4] = {acc1[i][jj].x, acc1[i][jj].y, acc1[i][jj].z, acc1[i][jj].w};
            float zr1[4] = {acc1[i][jj+2].x, acc1[i][jj+2].y, acc1[i][jj+2].z, acc1[i][jj+2].w};
            float zl2[4] = {acc2[i][jj].x, acc2[i][jj].y, acc2[i][jj].z, acc2[i][jj].w};
            float zr2[4] = {acc2[i][jj+2].x, acc2[i][jj+2].y, acc2[i][jj+2].z, acc2[i][jj+2].w};
            #pragma unroll
            for (int r = 0; r < 4; ++r) {
                int n = nbase + r;
                if (n < NN) {
                    float ov = sigm(zl1[r] + bl1) * (zr1[r] + br1)
                             + sigm(zl2[r] + bl2) * (zr2[r] + br2);
                    outp[(long)n * 64 + ol] = ov;
                }
            }
        }
    }
}

// GLU in transposed space, b split across blockIdx.z.
// kIdx 0/1: write dpb (bf16) + maxd (store/max).
// kIdx 2: FUSED FINAL -- compute max(old,d), stage into Ys (dead after acc
// loop), transpose in LDS, out[b][w][n][c] += max + (data+temb+semb)[w+2].
// Replaces final_t; saves maxd write + re-read (98 MB) + one launch.
__global__ __launch_bounds__(256) void glu_t(
    const float* __restrict__ Yd, const float* __restrict__ Ywing,
    const float* __restrict__ gw_all, const float* __restrict__ gb_all,
    int kIdx, ushort* __restrict__ dp, float* __restrict__ maxd,
    const float* __restrict__ data, const float* __restrict__ temb,
    const float* __restrict__ semb, float* __restrict__ out)
{
    const int w = blockIdx.y;
    const int b = blockIdx.z;
    const int m0 = blockIdx.x * 64;
    const int tid = threadIdx.x;
    const int tx = tid & 15, ty = tid >> 4;
    const float* Ydp = Yd + (long)w * YSLAB;
    const float* Ywp = Ywing + (long)w * YSLAB;
    ushort* dpp = dp + (long)w * TSLAB;
    float* mdp = maxd + (long)w * MSLAB;
    const float* gw = gw_all + (long)(w * 3 + kIdx) * 8192;
    const float* gb = gb_all + (w * 3 + kIdx) * 128;
    __shared__ float gws[64][132];
    __shared__ float Ys[64][68];
    #pragma unroll
    for (int p = 0; p < 8; ++p) {
        int r = p * 8 + (tid >> 5);
        int c0 = (tid & 31) * 4;
        *(float4*)&gws[r][c0] = *(const float4*)(gw + r * 128 + c0);
    }
    #pragma unroll
    for (int p = 0; p < 4; ++p) {
        int c = p * 16 + ty;
        long off = (long)(b * 64 + c) * MY + m0 + tx * 4;
        float4 v1 = *(const float4*)(Ydp + off);
        float4 v2 = *(const float4*)(Ywp + off);
        Ys[c][tx * 4 + 0] = v1.x + v2.x;
        Ys[c][tx * 4 + 1] = v1.y + v2.y;
        Ys[c][tx * 4 + 2] = v1.z + v2.z;
        Ys[c][tx * 4 + 3] = v1.w + v2.w;
    }
    __syncthreads();
    float acc[8][4] = {{0.f}};
    for (int c = 0; c < 64; ++c) {
        float4 ym = *(const float4*)&Ys[c][tx * 4];
        #pragma unroll
        for (int p = 0; p < 8; ++p) {
            float a = gws[c][ty + p * 16];
            acc[p][0] = fmaf(a, ym.x, acc[p][0]);
            acc[p][1] = fmaf(a, ym.y, acc[p][1]);
            acc[p][2] = fmaf(a, ym.z, acc[p][2]);
            acc[p][3] = fmaf(a, ym.w, acc[p][3]);
        }
    }
    if (kIdx < 2) {
        #pragma unroll
        for (int p = 0; p < 4; ++p) {
            int c = ty + p * 16;
            float bl = gb[c], br = gb[64 + c];
            long row = (long)(b * 64 + c) * KA + m0 + tx * 4;
            float d[4];
            #pragma unroll
            for (int q = 0; q < 4; ++q) {
                float zl = acc[p][q] + bl;
                float zr = acc[p + 4][q] + br;
                d[q] = zl * sigm(zr);
            }
            int mb = m0 + tx * 4;
            ushort4 u;
            u.x = (mb + 0 < NN) ? f2b(d[0]) : (ushort)0;
            u.y = (mb + 1 < NN) ? f2b(d[1]) : (ushort)0;
            u.z = (mb + 2 < NN) ? f2b(d[2]) : (ushort)0;
            u.w = (mb + 3 < NN) ? f2b(d[3]) : (ushort)0;
            *(ushort4*)(dpp + row) = u;
            if (kIdx == 0) {
                float4 m4 = {d[0], d[1], d[2], d[3]};
                *(float4*)(mdp + row) = m4;
            } else {
                float4 old = *(const float4*)(mdp + row);
                float4 m4;
                m4.x = fmaxf(old.x, d[0]); m4.y = fmaxf(old.y, d[1]);
                m4.z = fmaxf(old.z, d[2]); m4.w = fmaxf(old.w, d[3]);
                *(float4*)(mdp + row) = m4;
            }
        }
    } else {
        __syncthreads();   // all Ys reads done; reuse Ys as transpose buffer
        #pragma unroll
        for (int p = 0; p < 4; ++p) {
            int c = ty + p * 16;
            float bl = gb[c], br = gb[64 + c];
            long row = (long)(b * 64 + c) * KA + m0 + tx * 4;
            float4 old = *(const float4*)(mdp + row);
            float om[4] = {old.x, old.y, old.z, old.w};
            #pragma unroll
            for (int q = 0; q < 4; ++q) {
                float zl = acc[p][q] + bl;
                float zr = acc[p + 4][q] + br;
                Ys[c][tx * 4 + q] = fmaxf(om[q], zl * sigm(zr));
            }
        }
        __syncthreads();
        #pragma unroll
        for (int p = 0; p < 4; ++p) {
            int nl = p * 16 + ty;
            int n = m0 + nl;
            if (n < NN) {
                int c4 = tx * 4;
                long oidx = ((long)(b * WD + w) * NN + n) * 64 + c4;
                float4 o  = *(const float4*)(out + oidx);
                float4 dd = *(const float4*)(data + ((long)(b * TD + w + 2) * NN + n) * 64 + c4);
                float4 tv = *(const float4*)(temb + (w + 2) * 64 + c4);
                float4 sv = *(const float4*)(semb + n * 64 + c4);
                o.x += Ys[c4 + 0][nl] + dd.x + tv.x + sv.x;
                o.y += Ys[c4 + 1][nl] + dd.y + tv.y + sv.y;
                o.z += Ys[c4 + 2][nl] + dd.z + tv.z + sv.z;
                o.w += Ys[c4 + 3][nl] + dd.w + tv.w + sv.w;
                *(float4*)(out + oidx) = o;
            }
        }
    }
}

extern "C" void kernel_launch(void* const* d_in, const int* in_sizes, int n_in,
                              void* d_out, int out_size, void* d_ws, size_t ws_size,
                              hipStream_t stream) {
    const float* orig = (const float*)d_in[0];
    const float* data = (const float*)d_in[1];
    const float* adj  = (const float*)d_in[2];
    const float* c1w  = (const float*)d_in[3];
    const float* c1b  = (const float*)d_in[4];
    const float* c2w  = (const float*)d_in[5];
    const float* c2b  = (const float*)d_in[6];
    const float* temb = (const float*)d_in[7];
    const float* semb = (const float*)d_in[8];
    const float* gw   = (const float*)d_in[9];
    const float* gb   = (const float*)d_in[10];
    float* out = (float*)d_out;

    // One-time opt-in for 128 KB dynamic LDS (host-side attribute set; no
    // stream ops -> graph-capture safe; idempotent).
    static bool ldsAttrSet = false;
    if (!ldsAttrSet) {
        hipFuncSetAttribute((const void*)gemm_wing_d0,
                            hipFuncAttributeMaxDynamicSharedMemorySize, 131072);
        hipFuncSetAttribute((const void*)gemm_mfma,
                            hipFuncAttributeMaxDynamicSharedMemorySize, 131072);
        ldsAttrSet = true;
    }

    char* ws = (char*)d_ws;
    ushort* adjb = (ushort*)ws;                          ws += 3072L * 9024 * 2;   // 55.44 MB
    ushort* xT2  = (ushort*)ws;                          ws += 10L * TSLAB * 2;    // 30.80 MB
    ushort* dpb  = (ushort*)ws;                          ws += 8L * TSLAB * 2;     // 24.64 MB
    float*  ywing = (float*)ws;                          ws += 8L * YSLAB * 4;     // 50.33 MB
    float*  yd    = (float*)ws;                          ws += 8L * YSLAB * 4;     // 50.33 MB
    float*  maxd  = (float*)ws;                          // 49.28 MB  (total ~260.8 MB)

    // Aliases (dead until overwritten by later kernels, in-stream order):
    ushort* wb    = (ushort*)ywing;   // 128 KB, consumed by conv_mfma before wing gemm
    ushort* datab = (ushort*)yd;      // 31.5 MB, consumed before d0 gemm writes yd
    ushort* origb = (ushort*)maxd;    // 37.7 MB, consumed before glu_t writes maxd

    prep_all<<<dim3(49520), 256, 0, stream>>>(adj, data, orig, temb, semb, c1w, c2w,
                                              adjb, xT2, datab, origb, wb);

    conv_mfma<<<dim3(24, 64), 256, 0, stream>>>(datab, origb, wb, c1b, c2b, out);

    // wing + d0 combined, 256^2 8-wave phase-split GEMM (128 KB dynamic LDS)
    gemm_wing_d0<<<dim3(12, 2, 16), 512, 131072, stream>>>(xT2, adjb, ywing, yd);
    glu_t<<<dim3(47, 8, 8), 256, 0, stream>>>(yd, ywing, gw, gb, 0, dpb, maxd,
                                              data, temb, semb, out);
    gemm_mfma<<<dim3(12, 2, 8), 512, 131072, stream>>>(dpb, dpb, 1, TSLAB, adjb, 6000, 0, yd);
    glu_t<<<dim3(47, 8, 8), 256, 0, stream>>>(yd, ywing, gw, gb, 1, dpb, maxd,
                                              data, temb, semb, out);
    gemm_mfma<<<dim3(12, 2, 8), 512, 131072, stream>>>(dpb, dpb, 1, TSLAB, adjb, 6000, 0, yd);
    glu_t<<<dim3(47, 8, 8), 256, 0, stream>>>(yd, ywing, gw, gb, 2, dpb, maxd,
                                              data, temb, semb, out);
}

// Round 15
// 921.995 us; speedup vs baseline: 1.2507x; 1.0176x over previous
//
#include <hip/hip_runtime.h>
#include <hip/hip_bf16.h>
#include <math.h>

#define NN 3000
#define NP 3072          // padded node dim
#define KA 3008          // A-operand row stride (bf16 elems), k=node padded
#define KB 9024          // adj bf16 row stride
#define MY 3072          // Y fp32 row stride (padded node dim)
#define BD 8
#define TD 10
#define T0D 12
#define WD 8
#define TSLAB (512L*KA)  // bf16 elems per t-slab / d' slab
#define YSLAB (512L*MY)  // fp32 elems per Y slab
#define MSLAB (512L*KA)  // fp32 elems per maxd slab

typedef __attribute__((ext_vector_type(8))) short short8;
typedef __attribute__((ext_vector_type(4))) float floatx4;

__device__ __forceinline__ float sigm(float x) { return 1.0f / (1.0f + __expf(-x)); }
__device__ __forceinline__ ushort f2b(float f) {
    __hip_bfloat16 h = __float2bfloat16(f);
    return *reinterpret_cast<ushort*>(&h);
}
__device__ __forceinline__ void ld_lds16(const void* g, void* l) {
    __builtin_amdgcn_global_load_lds((const __attribute__((address_space(1))) unsigned int*)g,
                                     (__attribute__((address_space(3))) unsigned int*)l, 16, 0, 0);
}

// Fused prep. Block ranges:
//   [0, 27072)       adj  (3000x9000 f32 -> 3072x9024 bf16, pads zero)
//   [27072, 30832)   xt   (xT2 transposed; ALSO emits datab bf16 in load loop)
//   [30832, 49264)   db(orig, T0D)
//   [49264, 49520)   wb   (conv weight permute+pack)
__global__ __launch_bounds__(256) void prep_all(
    const float* __restrict__ adj, const float* __restrict__ data,
    const float* __restrict__ orig, const float* __restrict__ temb,
    const float* __restrict__ semb, const float* __restrict__ c1w,
    const float* __restrict__ c2w,
    ushort* __restrict__ adjb, ushort* __restrict__ xT2,
    ushort* __restrict__ datab, ushort* __restrict__ origb,
    ushort* __restrict__ wb)
{
    const int blk = blockIdx.x;
    const int tid = threadIdx.x;
    __shared__ float T[64][68];

    if (blk < 27072) {
        long i = (long)blk * 256 + tid;          // 3072*2256 quads
        if (i >= 3072L * 2256) return;
        int r  = (int)(i / 2256);
        int c4 = (int)(i % 2256) * 4;
        ushort4 u = {0, 0, 0, 0};
        if (r < NN && c4 < 9000) {
            float4 v = *(const float4*)(adj + (long)r * 9000 + c4);
            u.x = f2b(v.x); u.y = f2b(v.y); u.z = f2b(v.z); u.w = f2b(v.w);
        }
        *(ushort4*)(adjb + (long)r * KB + c4) = u;
    } else if (blk < 30832) {
        int id = blk - 27072;                    // x + 47*(b + 8*t)
        const int x = id % 47;  id /= 47;
        const int b = id & 7;
        const int t = id >> 3;
        const int m0 = x * 64;
        const int tx = tid & 15, ty = tid >> 4;
        #pragma unroll
        for (int p = 0; p < 4; ++p) {
            int nl = p * 16 + ty;
            int n = m0 + nl;
            int c4 = tx * 4;
            float4 v = {0.f, 0.f, 0.f, 0.f};
            ushort4 du = {0, 0, 0, 0};
            if (n < NN) {
                float4 dv = *(const float4*)(data + ((long)(b * TD + t) * NN + n) * 64 + c4);
                float4 tv = *(const float4*)(temb + t * 64 + c4);
                float4 sv = *(const float4*)(semb + n * 64 + c4);
                du.x = f2b(dv.x); du.y = f2b(dv.y); du.z = f2b(dv.z); du.w = f2b(dv.w);
                v.x = dv.x + tv.x + sv.x; v.y = dv.y + tv.y + sv.y;
                v.z = dv.z + tv.z + sv.z; v.w = dv.w + tv.w + sv.w;
            }
            *(ushort4*)(datab + ((long)(b * TD + t) * NP + n) * 64 + c4) = du;
            T[c4 + 0][nl] = v.x; T[c4 + 1][nl] = v.y;
            T[c4 + 2][nl] = v.z; T[c4 + 3][nl] = v.w;
        }
        __syncthreads();
        #pragma unroll
        for (int p = 0; p < 4; ++p) {
            int c = p * 16 + ty;
            int m4 = tx * 4;
            ushort4 u;
            u.x = f2b(T[c][m4 + 0]); u.y = f2b(T[c][m4 + 1]);
            u.z = f2b(T[c][m4 + 2]); u.w = f2b(T[c][m4 + 3]);
            *(ushort4*)(xT2 + ((long)t * 512 + b * 64 + c) * KA + m0 + m4) = u;
        }
    } else if (blk < 49264) {
        long i = (long)(blk - 30832) * 256 + tid; // quads: 8*T0D*3072*16
        long tot = 8L * T0D * NP * 16;
        if (i >= tot) return;
        int c4 = (int)(i & 15) * 4;
        long r = i >> 4;                 // (b*T0D+t)*3072 + n
        int n = (int)(r % NP);
        long bt = r / NP;
        ushort4 u = {0, 0, 0, 0};
        if (n < NN) {
            float4 v = *(const float4*)(orig + (bt * NN + n) * 64 + c4);
            u.x = f2b(v.x); u.y = f2b(v.y); u.z = f2b(v.z); u.w = f2b(v.w);
        }
        *(ushort4*)(origb + r * 64 + c4) = u;
    } else {
        int i = (blk - 49264) * 256 + tid;
        if (i >= 128 * 512) return;
        int r = i >> 9, k = i & 511;
        int q = r >> 6, jp = r & 63;
        int o = (jp < 32) ? (q * 32 + jp) : (64 + q * 32 + (jp - 32));
        int s = k >> 6, c = k & 63;
        float v = (s < 3) ? c1w[(o * 64 + c) * 3 + s] : c2w[(o * 64 + c) * 5 + (s - 3)];
        wb[i] = f2b(v);
    }
}

// ---------------------------------------------------------------------------
// 256x256 8-wave phase-split GEMM. R15 edit: barrier reduction 6->2 per K-tile.
// Cross-wave LDS publish happens ONLY at kh0/kh1 boundaries: per-wave
// vmcnt(4) (retiring its own kh loads) + one s_barrier publishes all waves'
// kh writes. P0->P1 and P2->P3 need no barrier (same data, proven landed);
// phase-exit barriers were redundant with the next publish point. Per-wave
// vmcnt FIFO ledger unchanged (P0-entry retires h0 pair, P2-entry h1 pair).
// ---------------------------------------------------------------------------
#define MFMA_BF16 __builtin_amdgcn_mfma_f32_16x16x32_bf16

__device__ __forceinline__ void gemm8_body(
    const ushort* __restrict__ A0, const ushort* __restrict__ A1, int nseg,
    const ushort* __restrict__ Badj, int colOff0, int colOff1,
    float* __restrict__ Yp, ushort* lds)
{
    const int m0 = blockIdx.x * 256;
    const int j0 = blockIdx.y * 256;
    const int tid = threadIdx.x;
    const int lane = tid & 63;
    const int wv = tid >> 6;                 // 0..7
    const int wjr = (wv >> 2) * 128;         // wave j-offset (2 rows of waves)
    const int wmr = (wv & 3) * 64;           // wave m-offset (4 cols of waves)
    const int half = (lane >> 4) & 3;
    const int rsub = lane & 15;
    const int hsw = (half ^ ((rsub >> 1) & 3)) * 8;
    const int kxs = ((lane & 3) ^ ((lane >> 3) & 3)) * 8;
    const int NT = 47 * nseg;

    ushort* sA0 = lds;
    ushort* sA1 = lds + 16384;
    ushort* sB0 = lds + 32768;
    ushort* sB1 = lds + 49152;

    floatx4 acc[8][4] = {};

    int offA[8], offB[4];
    #pragma unroll
    for (int i = 0; i < 8; ++i) offA[i] = (wjr + i * 16 + rsub) * 32 + hsw;
    #pragma unroll
    for (int j = 0; j < 4; ++j) offB[j] = (wmr + j * 16 + rsub) * 32 + hsw;

    const int dOff = wv * 1024;              // ushort units; +q*512, +h*8192

    const long rA = j0 + wv * 32 + (lane >> 2);
    const long rB = m0 + wv * 32 + (lane >> 2);
    const ushort* bA  = A0 + rA * KA + kxs;
    const ushort* bB  = Badj + colOff0 + rB * KB + kxs;
    const ushort* aA1 = A1 + rA * KA + kxs;
    const ushort* aB1 = Badj + colOff1 + rB * KB + kxs;
    int issued = 0;

    auto issueA = [&](ushort* dA, int h) {
        const ushort* g = bA + h * 32;
        ld_lds16(g,           dA + h * 8192 + dOff);
        ld_lds16(g + 16 * KA, dA + h * 8192 + 512 + dOff);
    };
    auto issueB = [&](ushort* dB, int h) {
        const ushort* g = bB + h * 32;
        ld_lds16(g,           dB + h * 8192 + dOff);
        ld_lds16(g + 16 * KB, dB + h * 8192 + 512 + dOff);
    };
    auto adv = [&]() {
        ++issued;
        if (issued == 47 && nseg == 2) { bA = aA1; bB = aB1; }
        else { bA += 64; bB += 64; }
    };

    // prologue: tile 0 fully issued into buf0 (8 loads outstanding)
    issueA(sA0, 0); issueB(sB0, 0); issueA(sA0, 1); issueB(sB0, 1); adv();

    for (int t = 0; t < NT; ++t) {
        ushort* cA = (t & 1) ? sA1 : sA0;
        ushort* cB = (t & 1) ? sB1 : sB0;
        ushort* nA = (t & 1) ? sA0 : sA1;
        ushort* nB = (t & 1) ? sB0 : sB1;
        const bool pre = (t + 1 < NT);
        short8 af[4], bf[4];

        // ==== kh0 publish: own loads retired + barrier -> all kh0 visible
        asm volatile("s_waitcnt vmcnt(4)" ::: "memory");
        __builtin_amdgcn_s_barrier();
        __builtin_amdgcn_sched_barrier(0);
        // ---- P0: (jh0, ks0)
        #pragma unroll
        for (int j = 0; j < 4; ++j) bf[j] = *(const short8*)(cB + offB[j]);
        #pragma unroll
        for (int i = 0; i < 4; ++i) af[i] = *(const short8*)(cA + offA[i]);
        if (pre) issueA(nA, 0);
        __builtin_amdgcn_s_setprio(1);
        #pragma unroll
        for (int i = 0; i < 4; ++i)
            #pragma unroll
            for (int j = 0; j < 4; ++j)
                acc[i][j] = MFMA_BF16(af[i], bf[j], acc[i][j], 0, 0, 0);
        __builtin_amdgcn_s_setprio(0);
        // ---- P1: (jh1, ks0) -- same kh0 data, no barrier needed
        #pragma unroll
        for (int i = 0; i < 4; ++i) af[i] = *(const short8*)(cA + offA[4 + i]);
        if (pre) issueB(nB, 0);
        __builtin_amdgcn_s_setprio(1);
        #pragma unroll
        for (int i = 0; i < 4; ++i)
            #pragma unroll
            for (int j = 0; j < 4; ++j)
                acc[4 + i][j] = MFMA_BF16(af[i], bf[j], acc[4 + i][j], 0, 0, 0);
        __builtin_amdgcn_s_setprio(0);

        // ==== kh1 publish
        if (t == NT - 1) asm volatile("s_waitcnt vmcnt(0)" ::: "memory");
        else             asm volatile("s_waitcnt vmcnt(4)" ::: "memory");
        __builtin_amdgcn_s_barrier();
        __builtin_amdgcn_sched_barrier(0);
        // ---- P2: (jh0, ks1)
        #pragma unroll
        for (int j = 0; j < 4; ++j) bf[j] = *(const short8*)(cB + 8192 + offB[j]);
        #pragma unroll
        for (int i = 0; i < 4; ++i) af[i] = *(const short8*)(cA + 8192 + offA[i]);
        if (pre) issueA(nA, 1);
        __builtin_amdgcn_s_setprio(1);
        #pragma unroll
        for (int i = 0; i < 4; ++i)
            #pragma unroll
            for (int j = 0; j < 4; ++j)
                acc[i][j] = MFMA_BF16(af[i], bf[j], acc[i][j], 0, 0, 0);
        __builtin_amdgcn_s_setprio(0);
        // ---- P3: (jh1, ks1) -- same kh1 data, no barrier needed
        #pragma unroll
        for (int i = 0; i < 4; ++i) af[i] = *(const short8*)(cA + 8192 + offA[4 + i]);
        if (pre) { issueB(nB, 1); adv(); }
        __builtin_amdgcn_s_setprio(1);
        #pragma unroll
        for (int i = 0; i < 4; ++i)
            #pragma unroll
            for (int j = 0; j < 4; ++j)
                acc[4 + i][j] = MFMA_BF16(af[i], bf[j], acc[4 + i][j], 0, 0, 0);
        __builtin_amdgcn_s_setprio(0);
    }

    #pragma unroll
    for (int i = 0; i < 8; ++i) {
        int jrow = j0 + wjr + i * 16 + half * 4;
        #pragma unroll
        for (int j = 0; j < 4; ++j) {
            int mcol = m0 + wmr + j * 16 + rsub;
            float* o = Yp + (long)jrow * MY + mcol;
            o[0L * MY] = acc[i][j].x;
            o[1L * MY] = acc[i][j].y;
            o[2L * MY] = acc[i][j].z;
            o[3L * MY] = acc[i][j].w;
        }
    }
}

// Generic per-w wrapper (d1/d2): grid (12, 2, 8), 512 thr, 128 KB dyn LDS
__global__ __launch_bounds__(512, 2) void gemm_mfma(
    const ushort* __restrict__ A0, const ushort* __restrict__ A1, int nseg, long aW,
    const ushort* __restrict__ Badj, int colOff0, int colOff1,
    float* __restrict__ Y)
{
    extern __shared__ ushort dynlds[];
    const int w = blockIdx.z;
    gemm8_body(A0 + (long)w * aW, A1 + (long)w * aW, nseg,
               Badj, colOff0, colOff1, Y + (long)w * YSLAB, dynlds);
}

// Combined wing + d0: grid (12, 2, 16): z<8 wing (nseg=2), z>=8 d0 (nseg=1).
__global__ __launch_bounds__(512, 2) void gemm_wing_d0(
    const ushort* __restrict__ xT2, const ushort* __restrict__ Badj,
    float* __restrict__ ywing, float* __restrict__ yd)
{
    extern __shared__ ushort dynlds[];
    const int zz = blockIdx.z;
    if (zz < 8) {
        gemm8_body(xT2 + (long)zz * TSLAB, xT2 + (long)(zz + 1) * TSLAB, 2,
                   Badj, 0, 3000, ywing + (long)zz * YSLAB, dynlds);
    } else {
        const int w = zz - 8;
        const ushort* a = xT2 + (long)(w + 2) * TSLAB;
        gemm8_body(a, a, 1, Badj, 6000, 0, yd + (long)w * YSLAB, dynlds);
    }
}

// Gated convs via MFMA with the verified 3-stage counted-vmcnt pipeline.
__global__ __launch_bounds__(256) void conv_mfma(
    const ushort* __restrict__ datab, const ushort* __restrict__ origb,
    const ushort* __restrict__ wb,
    const float* __restrict__ b1, const float* __restrict__ b2,
    float* __restrict__ out)
{
    const int b = blockIdx.y >> 3, wt = blockIdx.y & 7;
    const int n0 = blockIdx.x * 128;
    const int tid = threadIdx.x;
    const int lane = tid & 63;
    const int wv = tid >> 6;
    __shared__ ushort shA[3][4096];
    __shared__ ushort shB[3][4096];
    floatx4 acc1[4][4] = {};
    floatx4 acc2[4][4] = {};
    const int srow = wv * 16 + (lane >> 2);
    const int kswz = ((lane & 3) ^ ((lane >> 3) & 3)) * 8;
    const int wj = (wv >> 1) * 64, wm = (wv & 1) * 64;
    const int half = lane >> 4;
    const int rsub = lane & 15;
    const int hsw  = (half ^ ((rsub >> 1) & 3)) * 8;
    const int wOff = wv * 512;

    int offA[4], offB[4];
    #pragma unroll
    for (int i = 0; i < 4; ++i) {
        offA[i] = (wj + i * 16 + rsub) * 32 + hsw;
        offB[i] = (wm + i * 16 + rsub) * 32 + hsw;
    }

    auto stage = [&](int kt, ushort* dA, ushort* dB) {
        const int sl = kt >> 1, koff = (kt & 1) * 32;
        const ushort* Ab = (sl < 3) ? datab + (long)(b * TD + wt + sl) * NP * 64
                                    : origb + (long)(b * T0D + wt + (sl - 3)) * NP * 64;
        const ushort* gA = Ab + (long)(n0 + srow) * 64 + koff + kswz;
        ld_lds16(gA,           dA + wOff);
        ld_lds16(gA + 64 * 64, dA + 2048 + wOff);
        const ushort* gB = wb + (long)srow * 512 + kt * 32 + kswz;
        ld_lds16(gB,            dB + wOff);
        ld_lds16(gB + 64 * 512, dB + 2048 + wOff);
    };

    ushort *pA0 = shA[0], *pA1 = shA[1], *pA2 = shA[2];
    ushort *pB0 = shB[0], *pB1 = shB[1], *pB2 = shB[2];

    stage(0, pA0, pB0);
    stage(1, pA1, pB1);
    asm volatile("s_waitcnt vmcnt(4)" ::: "memory");
    __builtin_amdgcn_s_barrier();
    __builtin_amdgcn_sched_barrier(0);

    for (int s = 0; s < 16; ++s) {
        if (s + 2 < 16)
            stage(s + 2, pA2, pB2);
        short8 af[4], bf[4];
        #pragma unroll
        for (int i = 0; i < 4; ++i)
            af[i] = *(const short8*)(pA0 + offA[i]);
        #pragma unroll
        for (int i = 0; i < 4; ++i)
            bf[i] = *(const short8*)(pB0 + offB[i]);
        if (s < 6) {
            #pragma unroll
            for (int i = 0; i < 4; ++i)
                #pragma unroll
                for (int jj = 0; jj < 4; ++jj)
                    acc1[i][jj] = MFMA_BF16(af[i], bf[jj], acc1[i][jj], 0, 0, 0);
        } else {
            #pragma unroll
            for (int i = 0; i < 4; ++i)
                #pragma unroll
                for (int jj = 0; jj < 4; ++jj)
                    acc2[i][jj] = MFMA_BF16(af[i], bf[jj], acc2[i][jj], 0, 0, 0);
        }
        if (s + 2 < 16) {
            asm volatile("s_waitcnt vmcnt(4)" ::: "memory");
        } else if (s + 1 < 16) {
            asm volatile("s_waitcnt vmcnt(0)" ::: "memory");
        }
        __builtin_amdgcn_s_barrier();
        __builtin_amdgcn_sched_barrier(0);
        ushort* t;
        t = pA0; pA0 = pA1; pA1 = pA2; pA2 = t;
        t = pB0; pB0 = pB1; pB1 = pB2; pB2 = t;
    }

    const int q = wv & 1;
    float* outp = out + (long)(b * WD + wt) * NN * 64;
    #pragma unroll
    for (int i = 0; i < 4; ++i) {
        const int nbase = n0 + wj + i * 16 + half * 4;
        #pragma unroll
        for (int jj = 0; jj < 2; ++jj) {
            const int ol = q * 32 + jj * 16 + rsub;
            const float bl1 = b1[ol], br1 = b1[64 + ol];
            const float bl2 = b2[ol], br2 = b2[64 + ol];
            float zl1[4] = {acc1[i][jj].x, acc1[i][jj].y, acc1[i][jj].z, acc1[i][jj].w};
            float zr1[4] = {acc1[i][jj+2].x, acc1[i][jj+2].y, acc1[i][jj+2].z, acc1[i][jj+2].w};
            float zl2[4] = {acc2[i][jj].x, acc2[i][jj].y, acc2[i][jj].z, acc2[i][jj].w};
            float zr2[4] = {acc2[i][jj+2].x, acc2[i][jj+2].y, acc2[i][jj+2].z, acc2[i][jj+2].w};
            #pragma unroll
            for (int r = 0; r < 4; ++r) {
                int n = nbase + r;
                if (n < NN) {
                    float ov = sigm(zl1[r] + bl1) * (zr1[r] + br1)
                             + sigm(zl2[r] + bl2) * (zr2[r] + br2);
                    outp[(long)n * 64 + ol] = ov;
                }
            }
        }
    }
}

// GLU in transposed space, b split across blockIdx.z.
// kIdx 0/1: write dpb (bf16) + maxd (store/max).
// kIdx 2: FUSED FINAL -- compute max(old,d), stage into Ys, transpose in LDS,
// out[b][w][n][c] += max + (data+temb+semb)[w+2].
__global__ __launch_bounds__(256) void glu_t(
    const float* __restrict__ Yd, const float* __restrict__ Ywing,
    const float* __restrict__ gw_all, const float* __restrict__ gb_all,
    int kIdx, ushort* __restrict__ dp, float* __restrict__ maxd,
    const float* __restrict__ data, const float* __restrict__ temb,
    const float* __restrict__ semb, float* __restrict__ out)
{
    const int w = blockIdx.y;
    const int b = blockIdx.z;
    const int m0 = blockIdx.x * 64;
    const int tid = threadIdx.x;
    const int tx = tid & 15, ty = tid >> 4;
    const float* Ydp = Yd + (long)w * YSLAB;
    const float* Ywp = Ywing + (long)w * YSLAB;
    ushort* dpp = dp + (long)w * TSLAB;
    float* mdp = maxd + (long)w * MSLAB;
    const float* gw = gw_all + (long)(w * 3 + kIdx) * 8192;
    const float* gb = gb_all + (w * 3 + kIdx) * 128;
    __shared__ float gws[64][132];
    __shared__ float Ys[64][68];
    #pragma unroll
    for (int p = 0; p < 8; ++p) {
        int r = p * 8 + (tid >> 5);
        int c0 = (tid & 31) * 4;
        *(float4*)&gws[r][c0] = *(const float4*)(gw + r * 128 + c0);
    }
    #pragma unroll
    for (int p = 0; p < 4; ++p) {
        int c = p * 16 + ty;
        long off = (long)(b * 64 + c) * MY + m0 + tx * 4;
        float4 v1 = *(const float4*)(Ydp + off);
        float4 v2 = *(const float4*)(Ywp + off);
        Ys[c][tx * 4 + 0] = v1.x + v2.x;
        Ys[c][tx * 4 + 1] = v1.y + v2.y;
        Ys[c][tx * 4 + 2] = v1.z + v2.z;
        Ys[c][tx * 4 + 3] = v1.w + v2.w;
    }
    __syncthreads();
    float acc[8][4] = {{0.f}};
    for (int c = 0; c < 64; ++c) {
        float4 ym = *(const float4*)&Ys[c][tx * 4];
        #pragma unroll
        for (int p = 0; p < 8; ++p) {
            float a = gws[c][ty + p * 16];
            acc[p][0] = fmaf(a, ym.x, acc[p][0]);
            acc[p][1] = fmaf(a, ym.y, acc[p][1]);
            acc[p][2] = fmaf(a, ym.z, acc[p][2]);
            acc[p][3] = fmaf(a, ym.w, acc[p][3]);
        }
    }
    if (kIdx < 2) {
        #pragma unroll
        for (int p = 0; p < 4; ++p) {
            int c = ty + p * 16;
            float bl = gb[c], br = gb[64 + c];
            long row = (long)(b * 64 + c) * KA + m0 + tx * 4;
            float d[4];
            #pragma unroll
            for (int q = 0; q < 4; ++q) {
                float zl = acc[p][q] + bl;
                float zr = acc[p + 4][q] + br;
                d[q] = zl * sigm(zr);
            }
            int mb = m0 + tx * 4;
            ushort4 u;
            u.x = (mb + 0 < NN) ? f2b(d[0]) : (ushort)0;
            u.y = (mb + 1 < NN) ? f2b(d[1]) : (ushort)0;
            u.z = (mb + 2 < NN) ? f2b(d[2]) : (ushort)0;
            u.w = (mb + 3 < NN) ? f2b(d[3]) : (ushort)0;
            *(ushort4*)(dpp + row) = u;
            if (kIdx == 0) {
                float4 m4 = {d[0], d[1], d[2], d[3]};
                *(float4*)(mdp + row) = m4;
            } else {
                float4 old = *(const float4*)(mdp + row);
                float4 m4;
                m4.x = fmaxf(old.x, d[0]); m4.y = fmaxf(old.y, d[1]);
                m4.z = fmaxf(old.z, d[2]); m4.w = fmaxf(old.w, d[3]);
                *(float4*)(mdp + row) = m4;
            }
        }
    } else {
        __syncthreads();   // all Ys reads done; reuse Ys as transpose buffer
        #pragma unroll
        for (int p = 0; p < 4; ++p) {
            int c = ty + p * 16;
            float bl = gb[c], br = gb[64 + c];
            long row = (long)(b * 64 + c) * KA + m0 + tx * 4;
            float4 old = *(const float4*)(mdp + row);
            float om[4] = {old.x, old.y, old.z, old.w};
            #pragma unroll
            for (int q = 0; q < 4; ++q) {
                float zl = acc[p][q] + bl;
                float zr = acc[p + 4][q] + br;
                Ys[c][tx * 4 + q] = fmaxf(om[q], zl * sigm(zr));
            }
        }
        __syncthreads();
        #pragma unroll
        for (int p = 0; p < 4; ++p) {
            int nl = p * 16 + ty;
            int n = m0 + nl;
            if (n < NN) {
                int c4 = tx * 4;
                long oidx = ((long)(b * WD + w) * NN + n) * 64 + c4;
                float4 o  = *(const float4*)(out + oidx);
                float4 dd = *(const float4*)(data + ((long)(b * TD + w + 2) * NN + n) * 64 + c4);
                float4 tv = *(const float4*)(temb + (w + 2) * 64 + c4);
                float4 sv = *(const float4*)(semb + n * 64 + c4);
                o.x += Ys[c4 + 0][nl] + dd.x + tv.x + sv.x;
                o.y += Ys[c4 + 1][nl] + dd.y + tv.y + sv.y;
                o.z += Ys[c4 + 2][nl] + dd.z + tv.z + sv.z;
                o.w += Ys[c4 + 3][nl] + dd.w + tv.w + sv.w;
                *(float4*)(out + oidx) = o;
            }
        }
    }
}

extern "C" void kernel_launch(void* const* d_in, const int* in_sizes, int n_in,
                              void* d_out, int out_size, void* d_ws, size_t ws_size,
                              hipStream_t stream) {
    const float* orig = (const float*)d_in[0];
    const float* data = (const float*)d_in[1];
    const float* adj  = (const float*)d_in[2];
    const float* c1w  = (const float*)d_in[3];
    const float* c1b  = (const float*)d_in[4];
    const float* c2w  = (const float*)d_in[5];
    const float* c2b  = (const float*)d_in[6];
    const float* temb = (const float*)d_in[7];
    const float* semb = (const float*)d_in[8];
    const float* gw   = (const float*)d_in[9];
    const float* gb   = (const float*)d_in[10];
    float* out = (float*)d_out;

    // One-time opt-in for 128 KB dynamic LDS (host-side attribute set; no
    // stream ops -> graph-capture safe; idempotent).
    static bool ldsAttrSet = false;
    if (!ldsAttrSet) {
        hipFuncSetAttribute((const void*)gemm_wing_d0,
                            hipFuncAttributeMaxDynamicSharedMemorySize, 131072);
        hipFuncSetAttribute((const void*)gemm_mfma,
                            hipFuncAttributeMaxDynamicSharedMemorySize, 131072);
        ldsAttrSet = true;
    }

    char* ws = (char*)d_ws;
    ushort* adjb = (ushort*)ws;                          ws += 3072L * 9024 * 2;   // 55.44 MB
    ushort* xT2  = (ushort*)ws;                          ws += 10L * TSLAB * 2;    // 30.80 MB
    ushort* dpb  = (ushort*)ws;                          ws += 8L * TSLAB * 2;     // 24.64 MB
    float*  ywing = (float*)ws;                          ws += 8L * YSLAB * 4;     // 50.33 MB
    float*  yd    = (float*)ws;                          ws += 8L * YSLAB * 4;     // 50.33 MB
    float*  maxd  = (float*)ws;                          // 49.28 MB  (total ~260.8 MB)

    // Aliases (dead until overwritten by later kernels, in-stream order):
    ushort* wb    = (ushort*)ywing;   // 128 KB, consumed by conv_mfma before wing gemm
    ushort* datab = (ushort*)yd;      // 31.5 MB, consumed before d0 gemm writes yd
    ushort* origb = (ushort*)maxd;    // 37.7 MB, consumed before glu_t writes maxd

    prep_all<<<dim3(49520), 256, 0, stream>>>(adj, data, orig, temb, semb, c1w, c2w,
                                              adjb, xT2, datab, origb, wb);

    conv_mfma<<<dim3(24, 64), 256, 0, stream>>>(datab, origb, wb, c1b, c2b, out);

    // wing + d0 combined, 256^2 8-wave phase-split GEMM (128 KB dynamic LDS)
    gemm_wing_d0<<<dim3(12, 2, 16), 512, 131072, stream>>>(xT2, adjb, ywing, yd);
    glu_t<<<dim3(47, 8, 8), 256, 0, stream>>>(yd, ywing, gw, gb, 0, dpb, maxd,
                                              data, temb, semb, out);
    gemm_mfma<<<dim3(12, 2, 8), 512, 131072, stream>>>(dpb, dpb, 1, TSLAB, adjb, 6000, 0, yd);
    glu_t<<<dim3(47, 8, 8), 256, 0, stream>>>(yd, ywing, gw, gb, 1, dpb, maxd,
                                              data, temb, semb, out);
    gemm_mfma<<<dim3(12, 2, 8), 512, 131072, stream>>>(dpb, dpb, 1, TSLAB, adjb, 6000, 0, yd);
    glu_t<<<dim3(47, 8, 8), 256, 0, stream>>>(yd, ywing, gw, gb, 2, dpb, maxd,
                                              data, temb, semb, out);
}